// Round 1
// baseline (2345.244 us; speedup 1.0000x reference)
//
#include <hip/hip_runtime.h>

typedef float  __attribute__((ext_vector_type(4))) f32x4;
typedef int    __attribute__((ext_vector_type(4))) i32x4;
typedef unsigned short u16;

#define B    256
#define H    512
#define HIN  128
#define N    16384
#define RW   16
#define HT   32
#define KCAT 640          // HIN + H
#define RWN  262144       // RW*N
#define TS_OFF   67108864 // B*RW*N
#define PROB_OFF 67112960 // TS_OFF + B*RW

// ---------- helpers ----------
__device__ __forceinline__ u16 f2bf(float f) {
  unsigned u = __builtin_bit_cast(unsigned, f);
  u += 0x7FFFu + ((u >> 16) & 1u);         // RTNE
  return (u16)(u >> 16);
}
__device__ __forceinline__ float sigm(float x) { return 1.0f / (1.0f + expf(-x)); }

// v_mfma_f32_16x16x32_bf16, D=A*B+C in-place on d.
// A[m][k]: m=lane%16, k=8*(lane/16)+e (8 contiguous bf16 = 4 VGPRs)
// B[k][n]: n=lane%16, k=8*(lane/16)+e
// D[r][c]: c=lane%16, r=4*(lane/16)+reg      (verified layout family, learn_hip m89)
// s_nop 1 covers the VALU-write -> MFMA-read SrcA/B/C hazard (2 wait states).
__device__ __forceinline__ void mfma(f32x4& d, i32x4 a, i32x4 b) {
  asm volatile("s_nop 1\n\tv_mfma_f32_16x16x32_bf16 %0, %1, %2, %0"
               : "+v"(d) : "v"(a), "v"(b));
}
// MFMA-write -> VALU/VMEM-read hazard guard, tied to the acc so it can't be reordered away.
__device__ __forceinline__ void fence_acc(f32x4& v) {
  asm volatile("s_nop 7\n\ts_nop 7" : "+v"(v));
}

// ---------- prologue: weight repack to bf16 + misc init ----------
__global__ __launch_bounds__(256) void k_prep(
    const float* __restrict__ W_up, const float* __restrict__ W_down,
    const float* __restrict__ W_ih, const float* __restrict__ W_hh,
    const float* __restrict__ Wt_down, const float* __restrict__ b_ih,
    const float* __restrict__ b_hh, const float* __restrict__ inputs0,
    u16* __restrict__ Wup_b, u16* __restrict__ Wdn_b, u16* __restrict__ Wcat_b,
    u16* __restrict__ Wtd_b, float* __restrict__ bcomb, u16* __restrict__ xcat0,
    float* __restrict__ last_t)
{
  const int idx0 = blockIdx.x * 256 + threadIdx.x;
  const int stride = gridDim.x * 256;
  for (int i = idx0; i < N * H; i += stride) Wup_b[i] = f2bf(W_up[i]);
  for (int i = idx0; i < HIN * N; i += stride) Wdn_b[i] = f2bf(W_down[i]);
  for (int i = idx0; i < 4 * H * KCAT; i += stride) {
    int j = i / KCAT, k = i - j * KCAT;
    Wcat_b[i] = f2bf(k < HIN ? W_ih[j * HIN + k] : W_hh[j * H + (k - HIN)]);
  }
  for (int i = idx0; i < HT * H; i += stride) Wtd_b[i] = f2bf(Wt_down[i]);
  for (int i = idx0; i < 4 * H; i += stride) bcomb[i] = b_ih[i] + b_hh[i];
  for (int i = idx0; i < B * HIN; i += stride) {
    int b = i >> 7, k = i & 127;
    xcat0[b * KCAT + k] = f2bf(inputs0[i]);
  }
  for (int i = idx0; i < B; i += stride) last_t[i] = 0.0f;
}

__global__ __launch_bounds__(256) void k_lat(
    const float* __restrict__ latent, const float* __restrict__ Wc,
    const float* __restrict__ bc, float* __restrict__ latbuf)
{
  int idx = blockIdx.x * 256 + threadIdx.x;       // 256*128
  int b = idx >> 7, i = idx & 127;
  float acc = bc[i];
  for (int k = 0; k < 129; ++k) acc += latent[b * 129 + k] * Wc[i * 129 + k];
  latbuf[idx] = tanhf(acc);
}

__global__ __launch_bounds__(256) void k_sinit(
    const float* __restrict__ latbuf, const float* __restrict__ Ws,
    const float* __restrict__ bs, float* __restrict__ sinit)
{
  int idx = blockIdx.x * 256 + threadIdx.x;       // 256*512
  int b = idx >> 9, j = idx & 511;
  float acc = bs[j];
  for (int k = 0; k < HIN; ++k) acc += latbuf[b * HIN + k] * Ws[j * HIN + k];
  sinit[idx] = tanhf(acc);
}

__global__ __launch_bounds__(256) void k_h0c0(
    const float* __restrict__ sinit, const float* __restrict__ Wh,
    const float* __restrict__ bh, const float* __restrict__ Wcc,
    const float* __restrict__ bcc, float* __restrict__ cbuf, u16* __restrict__ xc0)
{
  int idx = blockIdx.x * 256 + threadIdx.x;       // 256*512
  int b = idx >> 9, j = idx & 511;
  float ha = bh[j], ca = bcc[j];
  for (int k = 0; k < H; ++k) {
    float sv = sinit[b * H + k];
    ha += sv * Wh[j * H + k];
    ca += sv * Wcc[j * H + k];
  }
  cbuf[idx] = tanhf(ca);
  xc0[b * KCAT + HIN + j] = f2bf(tanhf(ha));
}

// ---------- per-step K1: gates GEMM + LSTM pointwise ----------
// grid 256 = 8 row-blocks(32) x 32 col-blocks(16). wave w computes gate quadrant w.
__global__ __launch_bounds__(256) void k_lstm(
    const u16* __restrict__ xc, const u16* __restrict__ Wcat,
    const float* __restrict__ bcomb, float* __restrict__ cbuf, u16* __restrict__ xn)
{
  const int rb = blockIdx.x >> 5, cb = blockIdx.x & 31;
  const int wave = threadIdx.x >> 6, lane = threadIdx.x & 63;
  const int lr = lane & 15, lk = lane >> 4;
  const int m0 = rb * 32, j0 = cb * 16;
  const int gcol = wave * H + j0 + lr;            // gate column this lane's B-frag covers
  f32x4 acc[2] = {};
  const u16* brow  = Wcat + gcol * KCAT + 8 * lk;
  const u16* arow0 = xc + (m0 + lr) * KCAT + 8 * lk;
  const u16* arow1 = arow0 + 16 * KCAT;
  #pragma unroll 4
  for (int kk = 0; kk < KCAT; kk += 32) {
    i32x4 bfr = *(const i32x4*)(brow + kk);
    i32x4 a0  = *(const i32x4*)(arow0 + kk);
    i32x4 a1  = *(const i32x4*)(arow1 + kk);
    mfma(acc[0], a0, bfr);
    mfma(acc[1], a1, bfr);
  }
  fence_acc(acc[0]); fence_acc(acc[1]);
  __shared__ float q[4][32][17];
  float bias = bcomb[gcol];
  #pragma unroll
  for (int mi = 0; mi < 2; ++mi)
    #pragma unroll
    for (int rr = 0; rr < 4; ++rr)
      q[wave][16 * mi + 4 * lk + rr][lr] = acc[mi][rr] + bias;
  __syncthreads();
  for (int idx = threadIdx.x; idx < 512; idx += 256) {
    int r = idx >> 4, jj = idx & 15;
    int b = m0 + r, j = j0 + jj;
    float gi = q[0][r][jj], gf = q[1][r][jj], gg = q[2][r][jj], go = q[3][r][jj];
    float c  = cbuf[b * H + j];
    float c2 = sigm(gf) * c + sigm(gi) * tanhf(gg);
    float h2 = sigm(go) * tanhf(c2);
    cbuf[b * H + j] = c2;
    xn[b * KCAT + HIN + j] = f2bf(h2);
  }
}

// ---------- per-step K2: p GEMM + gumbel + softmax partial stats (+ fused td/t-pred) ----------
// grid 512 = 8 row-blocks(32) x 64 col-blocks(256); wave covers 64 cols.
__global__ __launch_bounds__(256) void k_pgemm(
    const u16* __restrict__ xn, const u16* __restrict__ Wup,
    const float* __restrict__ b_up, const float* __restrict__ gum,
    float* __restrict__ sbuf, float* __restrict__ stat_m, float* __restrict__ stat_l,
    const u16* __restrict__ Wtd, const float* __restrict__ bt_down,
    const float* __restrict__ Wt_pred, const float* __restrict__ du,
    float* __restrict__ t0)
{
  const int rb = blockIdx.x >> 6, cb = blockIdx.x & 63;
  const int wave = threadIdx.x >> 6, lane = threadIdx.x & 63;
  const int lr = lane & 15, lk = lane >> 4;
  const int m0 = rb * 32;
  const int n0 = cb * 256 + wave * 64;
  f32x4 acc[2][4] = {};
  const u16* a0 = xn + (m0 + lr) * KCAT + HIN + 8 * lk;
  const u16* a1 = a0 + 16 * KCAT;
  #pragma unroll 2
  for (int kk = 0; kk < H; kk += 32) {
    i32x4 af0 = *(const i32x4*)(a0 + kk);
    i32x4 af1 = *(const i32x4*)(a1 + kk);
    #pragma unroll
    for (int ni = 0; ni < 4; ++ni) {
      i32x4 bf = *(const i32x4*)(Wup + (n0 + 16 * ni + lr) * H + kk + 8 * lk);
      mfma(acc[0][ni], af0, bf);
      mfma(acc[1][ni], af1, bf);
    }
  }
  #pragma unroll
  for (int mi = 0; mi < 2; ++mi)
    #pragma unroll
    for (int ni = 0; ni < 4; ++ni) fence_acc(acc[mi][ni]);

  float bup_c[4];
  #pragma unroll
  for (int ni = 0; ni < 4; ++ni) bup_c[ni] = b_up[n0 + 16 * ni + lr];
  #pragma unroll
  for (int mi = 0; mi < 2; ++mi)
    #pragma unroll
    for (int rr = 0; rr < 4; ++rr) {
      int row = m0 + 16 * mi + 4 * lk + rr;
      const float* g = gum + row * N + n0 + lr;
      float* sp = sbuf + row * N + n0 + lr;
      float v0 = acc[mi][0][rr] + bup_c[0] + g[0];
      float v1 = acc[mi][1][rr] + bup_c[1] + g[16];
      float v2 = acc[mi][2][rr] + bup_c[2] + g[32];
      float v3 = acc[mi][3][rr] + bup_c[3] + g[48];
      sp[0] = v0; sp[16] = v1; sp[32] = v2; sp[48] = v3;
      float vm = fmaxf(fmaxf(v0, v1), fmaxf(v2, v3));
      #pragma unroll
      for (int off = 1; off < 16; off <<= 1) vm = fmaxf(vm, __shfl_xor(vm, off));
      float e = expf(v0 - vm) + expf(v1 - vm) + expf(v2 - vm) + expf(v3 - vm);
      #pragma unroll
      for (int off = 1; off < 16; off <<= 1) e += __shfl_xor(e, off);
      if (lr == 0) {
        int chunk = cb * 4 + wave;
        stat_m[chunk * B + row] = vm;
        stat_l[chunk * B + row] = e;
      }
    }

  // straggler: TimeDecoder td = tanh(h2 @ Wt_down^T + bt)*mask/keep ; t0 = min(td@Wt_pred^T, 1)
  if (cb == 0 && wave < 2) {
    f32x4 acc2[2] = {};
    const u16* at = xn + (m0 + wave * 16 + lr) * KCAT + HIN + 8 * lk;
    for (int kk = 0; kk < H; kk += 32) {
      i32x4 af = *(const i32x4*)(at + kk);
      mfma(acc2[0], af, *(const i32x4*)(Wtd + lr * H + kk + 8 * lk));
      mfma(acc2[1], af, *(const i32x4*)(Wtd + (16 + lr) * H + kk + 8 * lk));
    }
    fence_acc(acc2[0]); fence_acc(acc2[1]);
    float wp0 = Wt_pred[lr],  wp1 = Wt_pred[16 + lr];
    float bt0 = bt_down[lr],  bt1 = bt_down[16 + lr];
    #pragma unroll
    for (int rr = 0; rr < 4; ++rr) {
      int row = m0 + wave * 16 + 4 * lk + rr;
      float td0 = tanhf(acc2[0][rr] + bt0);
      float td1 = tanhf(acc2[1][rr] + bt1);
      td0 = (du[row * HT + lr]      < 0.8f) ? td0 * 1.25f : 0.0f;
      td1 = (du[row * HT + 16 + lr] < 0.8f) ? td1 * 1.25f : 0.0f;
      float part = td0 * wp0 + td1 * wp1;
      #pragma unroll
      for (int off = 1; off < 16; off <<= 1) part += __shfl_xor(part, off);
      if (lr == 0) t0[row] = fminf(part, 1.0f);
    }
  }
}

// ---------- per-step K3 (1 block): merge softmax stats + batch-global t constraints ----------
__global__ __launch_bounds__(1024) void k_mid(
    const float* __restrict__ stat_m, const float* __restrict__ stat_l,
    const float* __restrict__ t0, float* __restrict__ rowM, float* __restrict__ rowRcp,
    float* __restrict__ tcur, float* __restrict__ last_t,
    float* __restrict__ ts_out, int r)
{
  const int tid = threadIdx.x;
  const int row = tid & 255, q = tid >> 8;
  float m = -3.0e38f, l = 0.0f;
  for (int c = q * 64; c < q * 64 + 64; ++c) {
    float mc = stat_m[c * B + row], lc = stat_l[c * B + row];
    if (mc > m) { l = l * expf(m - mc) + lc; m = mc; }
    else        { l += lc * expf(mc - m); }
  }
  __shared__ float mL[4][256], lL[4][256], red[256];
  mL[q][row] = m; lL[q][row] = l;
  __syncthreads();
  float t = 0.0f;
  if (tid < 256) {
    m = mL[0][tid]; l = lL[0][tid];
    for (int q2 = 1; q2 < 4; ++q2) {
      float mc = mL[q2][tid], lc = lL[q2][tid];
      if (mc > m) { l = l * expf(m - mc) + lc; m = mc; }
      else        { l += lc * expf(mc - m); }
    }
    rowM[tid] = m; rowRcp[tid] = 1.0f / l;
    t = t0[tid];
    red[tid] = t;
  }
  __syncthreads();
  for (int s2 = 128; s2 > 0; s2 >>= 1) {
    if (tid < s2) red[tid] = fminf(red[tid], red[tid + s2]);
    __syncthreads();
  }
  float mn = red[0];
  __syncthreads();
  if (mn < 0.1f) t -= mn;
  if (tid < 256) red[tid] = t;
  __syncthreads();
  for (int s2 = 128; s2 > 0; s2 >>= 1) {
    if (tid < s2) red[tid] = fmaxf(red[tid], red[tid + s2]);
    __syncthreads();
  }
  float mx = red[0];
  if (tid < 256) {
    if (mx > 1.0f) t /= mx;
    float lt = last_t[tid];
    t = fminf(fmaxf(t, lt), 1.0f);
    last_t[tid] = t;
    tcur[tid] = t;
    ts_out[tid * RW + r] = t;
  }
}

// ---------- per-step K4: v = softmax out (written to rw) + Hg split-K partials ----------
// grid 512 = 4 row-blocks(64) x 128 node-chunks(128); wave owns 16 rows, full chunk.
__global__ __launch_bounds__(256) void k_vhg(
    const float* __restrict__ sbuf, const float* __restrict__ rowM,
    const float* __restrict__ rowRcp, const u16* __restrict__ Wdn,
    float* __restrict__ out_rw, float* __restrict__ HgPart, int r)
{
  const int rb = blockIdx.x >> 7, cb = blockIdx.x & 127;
  const int wave = threadIdx.x >> 6, lane = threadIdx.x & 63;
  const int lr = lane & 15, lk = lane >> 4;
  const int row = rb * 64 + wave * 16 + lr;
  const int n0 = cb * 128;
  const float M = rowM[row], R = rowRcp[row];
  const float* srow = sbuf + row * N + n0 + 8 * lk;
  float* orow = out_rw + (long)row * RWN + r * N + n0 + 8 * lk;
  f32x4 acc[8] = {};
  #pragma unroll
  for (int kk = 0; kk < 4; ++kk) {
    f32x4 s0 = *(const f32x4*)(srow + kk * 32);
    f32x4 s1 = *(const f32x4*)(srow + kk * 32 + 4);
    f32x4 w0, w1;
    #pragma unroll
    for (int e = 0; e < 4; ++e) { w0[e] = expf(s0[e] - M) * R; w1[e] = expf(s1[e] - M) * R; }
    *(f32x4*)(orow + kk * 32) = w0;
    *(f32x4*)(orow + kk * 32 + 4) = w1;
    i32x4 a;
    a[0] = (int)f2bf(w0[0]) | ((int)f2bf(w0[1]) << 16);
    a[1] = (int)f2bf(w0[2]) | ((int)f2bf(w0[3]) << 16);
    a[2] = (int)f2bf(w1[0]) | ((int)f2bf(w1[1]) << 16);
    a[3] = (int)f2bf(w1[2]) | ((int)f2bf(w1[3]) << 16);
    #pragma unroll
    for (int ni = 0; ni < 8; ++ni) {
      i32x4 bf = *(const i32x4*)(Wdn + (16 * ni + lr) * N + n0 + kk * 32 + 8 * lk);
      mfma(acc[ni], a, bf);
    }
  }
  #pragma unroll
  for (int ni = 0; ni < 8; ++ni) fence_acc(acc[ni]);
  float* hp = HgPart + cb * (B * HIN) + (rb * 64 + wave * 16) * HIN;
  #pragma unroll
  for (int ni = 0; ni < 8; ++ni)
    #pragma unroll
    for (int rr = 0; rr < 4; ++rr)
      hp[(4 * lk + rr) * HIN + 16 * ni + lr] = acc[ni][rr];
}

// ---------- per-step K5: reduce Hg partials + x2 = [Hg|Ht] @ W_vt^T ----------
__global__ __launch_bounds__(256) void k_x2(
    const float* __restrict__ HgPart, const float* __restrict__ tcur,
    const float* __restrict__ Wt_up, const float* __restrict__ bt_up,
    const float* __restrict__ W_vt, float* __restrict__ x2f, u16* __restrict__ xn)
{
  __shared__ float WvtL[128 * 161];
  __shared__ float catL[16][160];
  const int tid = threadIdx.x, r0 = blockIdx.x * 16;
  for (int i = tid; i < 128 * 160; i += 256) {
    int c = i / 160, m2 = i - c * 160;
    WvtL[c * 161 + m2] = W_vt[i];
  }
  for (int i = tid; i < 16 * HIN; i += 256) {
    int row = i >> 7, col = i & 127;
    float ssum = 0.0f;
    for (int cbk = 0; cbk < 128; ++cbk) ssum += HgPart[cbk * (B * HIN) + (r0 + row) * HIN + col];
    catL[row][col] = ssum;
  }
  for (int i = tid; i < 16 * HT; i += 256) {
    int row = i >> 5, j = i & 31;
    catL[row][HIN + j] = tcur[r0 + row] * Wt_up[j] + bt_up[j];
  }
  __syncthreads();
  const int row = tid >> 4, s = tid & 15;
  float o[8] = {};
  for (int m2 = 0; m2 < 160; ++m2) {
    float cv = catL[row][m2];
    #pragma unroll
    for (int u = 0; u < 8; ++u) o[u] += cv * WvtL[(s + 16 * u) * 161 + m2];
  }
  #pragma unroll
  for (int u = 0; u < 8; ++u) {
    int c = s + 16 * u;
    float val = o[u];
    x2f[(r0 + row) * HIN + c] = val;
    xn[(r0 + row) * KCAT + c] = f2bf(val);
  }
}

__global__ __launch_bounds__(256) void k_prob(
    const float* __restrict__ x2f, const float* __restrict__ W_prob, float* __restrict__ outp)
{
  int b = threadIdx.x;
  float acc = 0.0f;
  for (int i = 0; i < HIN; ++i) acc += x2f[b * HIN + i] * W_prob[i];
  outp[b] = acc;
}

// ---------- launch ----------
extern "C" void kernel_launch(void* const* d_in, const int* in_sizes, int n_in,
                              void* d_out, int out_size, void* d_ws, size_t ws_size,
                              hipStream_t stream) {
  (void)in_sizes; (void)n_in; (void)out_size; (void)ws_size;
  const float* latent  = (const float*)d_in[0];
  const float* inputs0 = (const float*)d_in[1];
  const float* Wc      = (const float*)d_in[2];
  const float* bc      = (const float*)d_in[3];
  const float* Ws      = (const float*)d_in[4];
  const float* bs      = (const float*)d_in[5];
  const float* Wh      = (const float*)d_in[6];
  const float* bh      = (const float*)d_in[7];
  const float* Wcc     = (const float*)d_in[8];
  const float* bcc     = (const float*)d_in[9];
  const float* W_ih    = (const float*)d_in[10];
  const float* b_ih    = (const float*)d_in[11];
  const float* W_hh    = (const float*)d_in[12];
  const float* b_hh    = (const float*)d_in[13];
  const float* W_up    = (const float*)d_in[14];
  const float* b_up    = (const float*)d_in[15];
  const float* W_down  = (const float*)d_in[16];
  const float* Wt_down = (const float*)d_in[17];
  const float* bt_down = (const float*)d_in[18];
  const float* Wt_pred = (const float*)d_in[19];
  const float* Wt_up   = (const float*)d_in[20];
  const float* bt_up   = (const float*)d_in[21];
  const float* W_vt    = (const float*)d_in[22];
  const float* W_prob  = (const float*)d_in[23];
  const float* gumbel  = (const float*)d_in[24];
  const float* drop_u  = (const float*)d_in[25];
  float* out = (float*)d_out;

  char* p = (char*)d_ws;
  auto alloc = [&](size_t bytes) { char* r = p; p += (bytes + 255) & ~(size_t)255; return r; };
  u16*   Wup_b  = (u16*)  alloc((size_t)N * H * 2);       // 16 MiB
  u16*   Wdn_b  = (u16*)  alloc((size_t)HIN * N * 2);     //  4 MiB
  u16*   Wcat_b = (u16*)  alloc((size_t)4 * H * KCAT * 2);
  u16*   Wtd_b  = (u16*)  alloc((size_t)HT * H * 2);
  float* bcomb  = (float*)alloc(4 * H * 4);
  u16*   xcat0  = (u16*)  alloc((size_t)B * KCAT * 2);
  u16*   xcat1  = (u16*)  alloc((size_t)B * KCAT * 2);
  float* cbuf   = (float*)alloc((size_t)B * H * 4);
  float* sinit  = (float*)alloc((size_t)B * H * 4);
  float* latbuf = (float*)alloc((size_t)B * HIN * 4);
  float* sbuf   = (float*)alloc((size_t)B * N * 4);       // 16 MiB
  float* stat_m = (float*)alloc((size_t)256 * B * 4);
  float* stat_l = (float*)alloc((size_t)256 * B * 4);
  float* rowM   = (float*)alloc(B * 4);
  float* rowRcp = (float*)alloc(B * 4);
  float* t0buf  = (float*)alloc(B * 4);
  float* tcur   = (float*)alloc(B * 4);
  float* last_t = (float*)alloc(B * 4);
  float* HgPart = (float*)alloc((size_t)128 * B * HIN * 4); // 16 MiB
  float* x2f    = (float*)alloc((size_t)B * HIN * 4);

  k_prep<<<2048, 256, 0, stream>>>(W_up, W_down, W_ih, W_hh, Wt_down, b_ih, b_hh, inputs0,
                                   Wup_b, Wdn_b, Wcat_b, Wtd_b, bcomb, xcat0, last_t);
  k_lat  <<<128, 256, 0, stream>>>(latent, Wc, bc, latbuf);
  k_sinit<<<512, 256, 0, stream>>>(latbuf, Ws, bs, sinit);
  k_h0c0 <<<512, 256, 0, stream>>>(sinit, Wh, bh, Wcc, bcc, cbuf, xcat0);

  for (int r = 0; r < 16; ++r) {
    u16* xc = (r & 1) ? xcat1 : xcat0;
    u16* xn = (r & 1) ? xcat0 : xcat1;
    k_lstm <<<256, 256, 0, stream>>>(xc, Wcat_b, bcomb, cbuf, xn);
    k_pgemm<<<512, 256, 0, stream>>>(xn, Wup_b, b_up, gumbel + (size_t)r * B * N,
                                     sbuf, stat_m, stat_l,
                                     Wtd_b, bt_down, Wt_pred, drop_u + (size_t)r * B * HT, t0buf);
    k_mid  <<<1, 1024, 0, stream>>>(stat_m, stat_l, t0buf, rowM, rowRcp, tcur, last_t,
                                    out + TS_OFF, r);
    k_vhg  <<<512, 256, 0, stream>>>(sbuf, rowM, rowRcp, Wdn_b, out, HgPart, r);
    k_x2   <<<16, 256, 0, stream>>>(HgPart, tcur, Wt_up, bt_up, W_vt, x2f, xn);
  }
  k_prob<<<1, 256, 0, stream>>>(x2f, W_prob, out + PROB_OFF);
}

// Round 2
// 1945.345 us; speedup vs baseline: 1.2056x; 1.2056x over previous
//
#include <hip/hip_runtime.h>

typedef float  __attribute__((ext_vector_type(4))) f32x4;
typedef int    __attribute__((ext_vector_type(4))) i32x4;
typedef unsigned short u16;

#define B    256
#define H    512
#define HIN  128
#define N    16384
#define RW   16
#define HT   32
#define KC2  672          // 160 (Hg|Ht) + 512 (h)
#define HOFF 160
#define RWN  262144       // RW*N
#define TS_OFF   67108864 // B*RW*N
#define PROB_OFF 67112960 // TS_OFF + B*RW

// ---------- helpers ----------
__device__ __forceinline__ u16 f2bf(float f) {
  unsigned u = __builtin_bit_cast(unsigned, f);
  u += 0x7FFFu + ((u >> 16) & 1u);         // RTNE
  return (u16)(u >> 16);
}
__device__ __forceinline__ float sigm(float x) { return 1.0f / (1.0f + expf(-x)); }

// no-nop MFMA: safe when A/B frags come from memory loads (waitcnt covers them)
__device__ __forceinline__ void mfma(f32x4& d, i32x4 a, i32x4 b) {
  asm volatile("v_mfma_f32_16x16x32_bf16 %0, %1, %2, %0" : "+v"(d) : "v"(a), "v"(b));
}
// nop MFMA: covers VALU-write -> MFMA-read hazard (acc init, f2bf-packed A)
__device__ __forceinline__ void mfma_n(f32x4& d, i32x4 a, i32x4 b) {
  asm volatile("s_nop 1\n\tv_mfma_f32_16x16x32_bf16 %0, %1, %2, %0" : "+v"(d) : "v"(a), "v"(b));
}
// MFMA-write -> VALU-read guard
__device__ __forceinline__ void fence_acc(f32x4& v) {
  asm volatile("s_nop 7\n\ts_nop 7" : "+v"(v));
}

// ---------- prologue ----------
__global__ __launch_bounds__(256) void k_prep(
    const float* __restrict__ W_up, const float* __restrict__ W_down,
    const float* __restrict__ W_hh, const float* __restrict__ Wt_down,
    const float* __restrict__ b_ih, const float* __restrict__ b_hh,
    u16* __restrict__ Wup_b, u16* __restrict__ Wdn_b, u16* __restrict__ Wfull,
    u16* __restrict__ Wtd_b, float* __restrict__ bcomb, u16* __restrict__ xcat0,
    float* __restrict__ tstep)
{
  const int idx0 = blockIdx.x * 256 + threadIdx.x;
  const int stride = gridDim.x * 256;
  for (int i = idx0; i < N * H; i += stride) Wup_b[i] = f2bf(W_up[i]);
  for (int i = idx0; i < HIN * N; i += stride) Wdn_b[i] = f2bf(W_down[i]);
  for (int i = idx0; i < 4 * H * H; i += stride) {
    int j = i >> 9, k = i & 511;
    Wfull[j * KC2 + HOFF + k] = f2bf(W_hh[i]);
  }
  for (int i = idx0; i < HT * H; i += stride) Wtd_b[i] = f2bf(Wt_down[i]);
  for (int i = idx0; i < 4 * H; i += stride) bcomb[i] = b_ih[i] + b_hh[i];
  for (int i = idx0; i < B * HOFF; i += stride) {
    int b = i / HOFF, m = i - b * HOFF;
    xcat0[b * KC2 + m] = 0;
  }
  for (int i = idx0; i < B; i += stride) tstep[i] = 0.0f;
}

// Wcomb = W_ih @ W_vt into Wfull cols 0..159; g0add = inputs0 @ W_ih^T; wpc = W_prob @ W_vt
__global__ __launch_bounds__(256) void k_fold(
    const float* __restrict__ W_ih, const float* __restrict__ W_vt,
    const float* __restrict__ inputs0, const float* __restrict__ W_prob,
    u16* __restrict__ Wfull, float* __restrict__ g0add, float* __restrict__ wpc)
{
  int idx = blockIdx.x * 256 + threadIdx.x;
  if (idx < 2048 * 160) {
    int j = idx / 160, m = idx - j * 160;
    float a = 0.0f;
    for (int c = 0; c < HIN; ++c) a += W_ih[j * HIN + c] * W_vt[c * 160 + m];
    Wfull[j * KC2 + m] = f2bf(a);
  } else if (idx < 2048 * 160 + 256 * 2048) {
    int i2 = idx - 2048 * 160;
    int b = i2 >> 11, j = i2 & 2047;
    float a = 0.0f;
    for (int k = 0; k < HIN; ++k) a += inputs0[b * HIN + k] * W_ih[j * HIN + k];
    g0add[i2] = a;
  } else if (idx < 2048 * 160 + 256 * 2048 + 160) {
    int m = idx - (2048 * 160 + 256 * 2048);
    float a = 0.0f;
    for (int k = 0; k < HIN; ++k) a += W_prob[k] * W_vt[k * 160 + m];
    wpc[m] = a;
  }
}

__global__ __launch_bounds__(256) void k_lat(
    const float* __restrict__ latent, const float* __restrict__ Wc,
    const float* __restrict__ bc, float* __restrict__ latbuf)
{
  int idx = blockIdx.x * 256 + threadIdx.x;       // 256*128
  int b = idx >> 7, i = idx & 127;
  float acc = bc[i];
  for (int k = 0; k < 129; ++k) acc += latent[b * 129 + k] * Wc[i * 129 + k];
  latbuf[idx] = tanhf(acc);
}

__global__ __launch_bounds__(256) void k_sinit(
    const float* __restrict__ latbuf, const float* __restrict__ Ws,
    const float* __restrict__ bs, float* __restrict__ sinit)
{
  int idx = blockIdx.x * 256 + threadIdx.x;       // 256*512
  int b = idx >> 9, j = idx & 511;
  float acc = bs[j];
  for (int k = 0; k < HIN; ++k) acc += latbuf[b * HIN + k] * Ws[j * HIN + k];
  sinit[idx] = tanhf(acc);
}

__global__ __launch_bounds__(256) void k_h0c0(
    const float* __restrict__ sinit, const float* __restrict__ Wh,
    const float* __restrict__ bh, const float* __restrict__ Wcc,
    const float* __restrict__ bcc, float* __restrict__ cbuf, u16* __restrict__ xc0)
{
  int idx = blockIdx.x * 256 + threadIdx.x;       // 256*512
  int b = idx >> 9, j = idx & 511;
  float ha = bh[j], ca = bcc[j];
  for (int k = 0; k < H; ++k) {
    float sv = sinit[b * H + k];
    ha += sv * Wh[j * H + k];
    ca += sv * Wcc[j * H + k];
  }
  cbuf[idx] = tanhf(ca);
  xc0[b * KC2 + HOFF + j] = f2bf(tanhf(ha));
}

// ---------- per-step K1: gates GEMM (K=672 fused [Hg|Ht|h]) + LSTM pointwise ----------
// grid 256 = 8 rb(32 rows) x 32 cb(16 cols/gate); wave = gate quadrant.
__global__ __launch_bounds__(256) void k_lstm(
    const u16* __restrict__ xc, const u16* __restrict__ Wfull,
    const float* __restrict__ bcomb, float* __restrict__ cbuf,
    u16* __restrict__ xn, const float* __restrict__ g0)
{
  const int rb = blockIdx.x >> 5, cb = blockIdx.x & 31;
  const int wave = threadIdx.x >> 6, lane = threadIdx.x & 63;
  const int lr = lane & 15, lk = lane >> 4;
  const int m0 = rb * 32, j0 = cb * 16;
  const int gcol = wave * H + j0 + lr;
  f32x4 acc[2] = {};
  const u16* brow  = Wfull + gcol * KC2 + 8 * lk;
  const u16* arow0 = xc + (m0 + lr) * KC2 + 8 * lk;
  const u16* arow1 = arow0 + 16 * KC2;
  {
    i32x4 bfr = *(const i32x4*)(brow);
    mfma_n(acc[0], *(const i32x4*)(arow0), bfr);
    mfma_n(acc[1], *(const i32x4*)(arow1), bfr);
  }
  #pragma unroll 4
  for (int kk = 32; kk < KC2; kk += 32) {
    i32x4 bfr = *(const i32x4*)(brow + kk);
    mfma(acc[0], *(const i32x4*)(arow0 + kk), bfr);
    mfma(acc[1], *(const i32x4*)(arow1 + kk), bfr);
  }
  fence_acc(acc[0]); fence_acc(acc[1]);
  __shared__ float q[4][32][17];
  float bias = bcomb[gcol];
  #pragma unroll
  for (int mi = 0; mi < 2; ++mi)
    #pragma unroll
    for (int rr = 0; rr < 4; ++rr)
      q[wave][16 * mi + 4 * lk + rr][lr] = acc[mi][rr] + bias;
  __syncthreads();
  for (int idx = threadIdx.x; idx < 512; idx += 256) {
    int r2 = idx >> 4, jj = idx & 15;
    int b = m0 + r2, j = j0 + jj;
    float gi = q[0][r2][jj], gf = q[1][r2][jj], gg = q[2][r2][jj], go = q[3][r2][jj];
    if (g0) {
      const float* gp = g0 + b * 2048 + j;
      gi += gp[0]; gf += gp[512]; gg += gp[1024]; go += gp[1536];
    }
    float c  = cbuf[b * H + j];
    float c2 = sigm(gf) * c + sigm(gi) * tanhf(gg);
    float h2 = sigm(go) * tanhf(c2);
    cbuf[b * H + j] = c2;
    xn[b * KC2 + HOFF + j] = f2bf(h2);
  }
}

// ---------- per-step K2: p GEMM + gumbel + per-block softmax stats + td/t0 straggler ----------
// grid 512 = 8 rb(32 rows) x 64 cb(256 cols); wave covers 64 cols.
__global__ __launch_bounds__(256) void k_pgemm(
    const u16* __restrict__ xn, const u16* __restrict__ Wup,
    const float* __restrict__ b_up, const float* __restrict__ gum,
    float* __restrict__ sbuf, float* __restrict__ stat_m, float* __restrict__ stat_l,
    const u16* __restrict__ Wtd, const float* __restrict__ bt_down,
    const float* __restrict__ Wt_pred, const float* __restrict__ du,
    float* __restrict__ t0)
{
  const int rb = blockIdx.x >> 6, cb = blockIdx.x & 63;
  const int wave = threadIdx.x >> 6, lane = threadIdx.x & 63;
  const int lr = lane & 15, lk = lane >> 4;
  const int m0 = rb * 32;
  const int n0 = cb * 256 + wave * 64;
  f32x4 acc[2][4] = {};
  const u16* a0 = xn + (m0 + lr) * KC2 + HOFF + 8 * lk;
  const u16* a1 = a0 + 16 * KC2;
  const u16* bbase = Wup + (n0 + lr) * H + 8 * lk;
  {
    i32x4 af0 = *(const i32x4*)(a0);
    i32x4 af1 = *(const i32x4*)(a1);
    #pragma unroll
    for (int ni = 0; ni < 4; ++ni) {
      i32x4 bf = *(const i32x4*)(bbase + ni * 16 * H);
      mfma_n(acc[0][ni], af0, bf);
      mfma_n(acc[1][ni], af1, bf);
    }
  }
  #pragma unroll 3
  for (int kk = 32; kk < H; kk += 32) {
    i32x4 af0 = *(const i32x4*)(a0 + kk);
    i32x4 af1 = *(const i32x4*)(a1 + kk);
    #pragma unroll
    for (int ni = 0; ni < 4; ++ni) {
      i32x4 bf = *(const i32x4*)(bbase + ni * 16 * H + kk);
      mfma(acc[0][ni], af0, bf);
      mfma(acc[1][ni], af1, bf);
    }
  }
  #pragma unroll
  for (int mi = 0; mi < 2; ++mi)
    #pragma unroll
    for (int ni = 0; ni < 4; ++ni) fence_acc(acc[mi][ni]);

  __shared__ float sm[4][32], sl[4][32];
  float bup_c[4];
  #pragma unroll
  for (int ni = 0; ni < 4; ++ni) bup_c[ni] = b_up[n0 + 16 * ni + lr];
  #pragma unroll
  for (int mi = 0; mi < 2; ++mi)
    #pragma unroll
    for (int rr = 0; rr < 4; ++rr) {
      int rl = 16 * mi + 4 * lk + rr;
      int row = m0 + rl;
      const float* g = gum + (size_t)row * N + n0 + lr;
      float* sp = sbuf + (size_t)row * N + n0 + lr;
      float v0 = acc[mi][0][rr] + bup_c[0] + g[0];
      float v1 = acc[mi][1][rr] + bup_c[1] + g[16];
      float v2 = acc[mi][2][rr] + bup_c[2] + g[32];
      float v3 = acc[mi][3][rr] + bup_c[3] + g[48];
      sp[0] = v0; sp[16] = v1; sp[32] = v2; sp[48] = v3;
      float vm = fmaxf(fmaxf(v0, v1), fmaxf(v2, v3));
      #pragma unroll
      for (int off = 1; off < 16; off <<= 1) vm = fmaxf(vm, __shfl_xor(vm, off));
      float e = expf(v0 - vm) + expf(v1 - vm) + expf(v2 - vm) + expf(v3 - vm);
      #pragma unroll
      for (int off = 1; off < 16; off <<= 1) e += __shfl_xor(e, off);
      if (lr == 0) { sm[wave][rl] = vm; sl[wave][rl] = e; }
    }
  __syncthreads();
  if (threadIdx.x < 32) {
    float m = sm[0][threadIdx.x], l = sl[0][threadIdx.x];
    #pragma unroll
    for (int w = 1; w < 4; ++w) {
      float mc = sm[w][threadIdx.x], lc = sl[w][threadIdx.x];
      if (mc > m) { l = l * expf(m - mc) + lc; m = mc; }
      else        { l += lc * expf(mc - m); }
    }
    stat_m[cb * B + m0 + threadIdx.x] = m;
    stat_l[cb * B + m0 + threadIdx.x] = l;
  }

  // straggler: td = tanh(h2 @ Wt_down^T + bt)*mask/keep ; t0 = min(td @ Wt_pred^T, 1)
  if (cb == 0 && wave < 2) {
    f32x4 acc2[2] = {};
    const u16* at = xn + (m0 + wave * 16 + lr) * KC2 + HOFF + 8 * lk;
    {
      i32x4 af = *(const i32x4*)(at);
      mfma_n(acc2[0], af, *(const i32x4*)(Wtd + lr * H + 8 * lk));
      mfma_n(acc2[1], af, *(const i32x4*)(Wtd + (16 + lr) * H + 8 * lk));
    }
    for (int kk = 32; kk < H; kk += 32) {
      i32x4 af = *(const i32x4*)(at + kk);
      mfma(acc2[0], af, *(const i32x4*)(Wtd + lr * H + kk + 8 * lk));
      mfma(acc2[1], af, *(const i32x4*)(Wtd + (16 + lr) * H + kk + 8 * lk));
    }
    fence_acc(acc2[0]); fence_acc(acc2[1]);
    float wp0 = Wt_pred[lr],  wp1 = Wt_pred[16 + lr];
    float bt0 = bt_down[lr],  bt1 = bt_down[16 + lr];
    #pragma unroll
    for (int rr = 0; rr < 4; ++rr) {
      int row = m0 + wave * 16 + 4 * lk + rr;
      float td0 = tanhf(acc2[0][rr] + bt0);
      float td1 = tanhf(acc2[1][rr] + bt1);
      td0 = (du[row * HT + lr]      < 0.8f) ? td0 * 1.25f : 0.0f;
      td1 = (du[row * HT + 16 + lr] < 0.8f) ? td1 * 1.25f : 0.0f;
      float part = td0 * wp0 + td1 * wp1;
      #pragma unroll
      for (int off = 1; off < 16; off <<= 1) part += __shfl_xor(part, off);
      if (lr == 0) t0[row] = fminf(part, 1.0f);
    }
  }
}

// ---------- per-step K3: stat merge (in-block) + v write + Hg split-K partials ----------
// grid 512 = 8 rb(32 rows) x 64 cb(256 cols); wave = (wr rowhalf, wc colhalf of 128)
__global__ __launch_bounds__(256) void k_vhg(
    const float* __restrict__ sbuf, const float* __restrict__ stat_m,
    const float* __restrict__ stat_l, const u16* __restrict__ Wdn,
    float* __restrict__ out_rw, float* __restrict__ HgPart, int r)
{
  const int rb = blockIdx.x >> 6, cb = blockIdx.x & 63;
  const int tid = threadIdx.x;
  const int wave = tid >> 6, lane = tid & 63;
  const int lr = lane & 15, lk = lane >> 4;
  const int wr = wave >> 1, wc = wave & 1;
  const int m0 = rb * 32;
  __shared__ float rowM_s[32], rowR_s[32];
  if (tid < 32) {
    int row = m0 + tid;
    float m = -3.0e38f, l = 0.0f;
    for (int c = 0; c < 64; ++c) {
      float mc = stat_m[c * B + row], lc = stat_l[c * B + row];
      if (mc > m) { l = l * expf(m - mc) + lc; m = mc; }
      else        { l += lc * expf(mc - m); }
    }
    rowM_s[tid] = m; rowR_s[tid] = 1.0f / l;
  }
  __syncthreads();
  const int row0 = m0 + wr * 16;
  const int nb = cb * 256 + wc * 128;
  const float M = rowM_s[wr * 16 + lr], R = rowR_s[wr * 16 + lr];
  const float* srow = sbuf + (size_t)(row0 + lr) * N + nb + 8 * lk;
  float* orow = out_rw + (size_t)(row0 + lr) * RWN + r * N + nb + 8 * lk;
  f32x4 acc[8] = {};
  #pragma unroll
  for (int kk = 0; kk < 4; ++kk) {
    f32x4 s0 = *(const f32x4*)(srow + kk * 32);
    f32x4 s1 = *(const f32x4*)(srow + kk * 32 + 4);
    f32x4 w0, w1;
    #pragma unroll
    for (int e = 0; e < 4; ++e) { w0[e] = expf(s0[e] - M) * R; w1[e] = expf(s1[e] - M) * R; }
    *(f32x4*)(orow + kk * 32) = w0;
    *(f32x4*)(orow + kk * 32 + 4) = w1;
    i32x4 a;
    a[0] = (int)f2bf(w0[0]) | ((int)f2bf(w0[1]) << 16);
    a[1] = (int)f2bf(w0[2]) | ((int)f2bf(w0[3]) << 16);
    a[2] = (int)f2bf(w1[0]) | ((int)f2bf(w1[1]) << 16);
    a[3] = (int)f2bf(w1[2]) | ((int)f2bf(w1[3]) << 16);
    #pragma unroll
    for (int ni = 0; ni < 8; ++ni) {
      i32x4 bf = *(const i32x4*)(Wdn + (size_t)(16 * ni + lr) * N + nb + kk * 32 + 8 * lk);
      mfma_n(acc[ni], a, bf);
    }
  }
  #pragma unroll
  for (int ni = 0; ni < 8; ++ni) fence_acc(acc[ni]);
  const int chunk = cb * 2 + wc;
  float* hp = HgPart + (size_t)chunk * (B * HIN);
  #pragma unroll
  for (int ni = 0; ni < 8; ++ni)
    #pragma unroll
    for (int rr = 0; rr < 4; ++rr)
      hp[(row0 + 4 * lk + rr) * HIN + 16 * ni + lr] = acc[ni][rr];
}

// ---------- per-step K4: parallel Hg reduce + t constraints + Ht/ts writes ----------
// grid 128 x 256 threads; each thread one (b,c) of Hg; each block owns 2 batch rows.
__global__ __launch_bounds__(256) void k_hgred(
    const float* __restrict__ HgPart, const float* __restrict__ t0,
    float* __restrict__ tstep, const float* __restrict__ Wt_up,
    const float* __restrict__ bt_up, float* __restrict__ ts_out,
    u16* __restrict__ xn, float* __restrict__ Hgf, int r)
{
  const int tid = threadIdx.x;
  const int idx = blockIdx.x * 256 + tid;
  float s0 = 0.f, s1 = 0.f, s2 = 0.f, s3 = 0.f;
  #pragma unroll 4
  for (int c = 0; c < 128; c += 4) {
    s0 += HgPart[(size_t)(c + 0) * (B * HIN) + idx];
    s1 += HgPart[(size_t)(c + 1) * (B * HIN) + idx];
    s2 += HgPart[(size_t)(c + 2) * (B * HIN) + idx];
    s3 += HgPart[(size_t)(c + 3) * (B * HIN) + idx];
  }
  float hg = (s0 + s1) + (s2 + s3);

  __shared__ float red[256], tl[256];
  float tv = t0[tid];
  red[tid] = tv; __syncthreads();
  for (int s = 128; s > 0; s >>= 1) {
    if (tid < s) red[tid] = fminf(red[tid], red[tid + s]);
    __syncthreads();
  }
  float mn = red[0]; __syncthreads();
  if (mn < 0.1f) tv -= mn;
  red[tid] = tv; __syncthreads();
  for (int s = 128; s > 0; s >>= 1) {
    if (tid < s) red[tid] = fmaxf(red[tid], red[tid + s]);
    __syncthreads();
  }
  float mx = red[0];
  if (mx > 1.0f) tv /= mx;
  tv = fminf(fmaxf(tv, tstep[r * B + tid]), 1.0f);
  tl[tid] = tv; __syncthreads();

  int b = idx >> 7, c = idx & 127;
  xn[b * KC2 + c] = f2bf(hg);
  Hgf[idx] = hg;
  const int b0 = blockIdx.x * 2;
  if (tid < 64) {
    int bb = b0 + (tid >> 5), j = tid & 31;
    xn[bb * KC2 + HIN + j] = f2bf(tl[bb] * Wt_up[j] + bt_up[j]);
  }
  if (tid < 2) {
    int bb = b0 + tid;
    tstep[(r + 1) * B + bb] = tl[bb];
    ts_out[bb * RW + r] = tl[bb];
  }
}

__global__ __launch_bounds__(256) void k_prob(
    const float* __restrict__ Hgf, const float* __restrict__ tstep,
    const float* __restrict__ Wt_up, const float* __restrict__ bt_up,
    const float* __restrict__ wpc, float* __restrict__ outp)
{
  int b = threadIdx.x;
  float acc = 0.0f;
  for (int m = 0; m < HIN; ++m) acc += Hgf[b * HIN + m] * wpc[m];
  float tv = tstep[16 * B + b];
  for (int j = 0; j < HT; ++j) acc += (tv * Wt_up[j] + bt_up[j]) * wpc[HIN + j];
  outp[b] = acc;
}

// ---------- launch ----------
extern "C" void kernel_launch(void* const* d_in, const int* in_sizes, int n_in,
                              void* d_out, int out_size, void* d_ws, size_t ws_size,
                              hipStream_t stream) {
  (void)in_sizes; (void)n_in; (void)out_size; (void)ws_size;
  const float* latent  = (const float*)d_in[0];
  const float* inputs0 = (const float*)d_in[1];
  const float* Wc      = (const float*)d_in[2];
  const float* bc      = (const float*)d_in[3];
  const float* Ws      = (const float*)d_in[4];
  const float* bs      = (const float*)d_in[5];
  const float* Wh      = (const float*)d_in[6];
  const float* bh      = (const float*)d_in[7];
  const float* Wcc     = (const float*)d_in[8];
  const float* bcc     = (const float*)d_in[9];
  const float* W_ih    = (const float*)d_in[10];
  const float* b_ih    = (const float*)d_in[11];
  const float* W_hh    = (const float*)d_in[12];
  const float* b_hh    = (const float*)d_in[13];
  const float* W_up    = (const float*)d_in[14];
  const float* b_up    = (const float*)d_in[15];
  const float* W_down  = (const float*)d_in[16];
  const float* Wt_down = (const float*)d_in[17];
  const float* bt_down = (const float*)d_in[18];
  const float* Wt_pred = (const float*)d_in[19];
  const float* Wt_up   = (const float*)d_in[20];
  const float* bt_up   = (const float*)d_in[21];
  const float* W_vt    = (const float*)d_in[22];
  const float* W_prob  = (const float*)d_in[23];
  const float* gumbel  = (const float*)d_in[24];
  const float* drop_u  = (const float*)d_in[25];
  float* out = (float*)d_out;

  char* p = (char*)d_ws;
  auto alloc = [&](size_t bytes) { char* r = p; p += (bytes + 255) & ~(size_t)255; return r; };
  u16*   Wup_b  = (u16*)  alloc((size_t)N * H * 2);
  u16*   Wdn_b  = (u16*)  alloc((size_t)HIN * N * 2);
  u16*   Wfull_b= (u16*)  alloc((size_t)4 * H * KC2 * 2);
  u16*   Wtd_b  = (u16*)  alloc((size_t)HT * H * 2);
  float* bcomb  = (float*)alloc(4 * H * 4);
  u16*   xcat0  = (u16*)  alloc((size_t)B * KC2 * 2);
  u16*   xcat1  = (u16*)  alloc((size_t)B * KC2 * 2);
  float* cbuf   = (float*)alloc((size_t)B * H * 4);
  float* sinit  = (float*)alloc((size_t)B * H * 4);
  float* latbuf = (float*)alloc((size_t)B * HIN * 4);
  float* sbuf   = (float*)alloc((size_t)B * N * 4);
  float* stat_m = (float*)alloc((size_t)64 * B * 4);
  float* stat_l = (float*)alloc((size_t)64 * B * 4);
  float* t0buf  = (float*)alloc(B * 4);
  float* tstep  = (float*)alloc((size_t)17 * B * 4);
  float* HgPart = (float*)alloc((size_t)128 * B * HIN * 4);
  float* Hgf    = (float*)alloc((size_t)B * HIN * 4);
  float* g0add  = (float*)alloc((size_t)B * 4 * H * 4);
  float* wpc    = (float*)alloc(160 * 4);

  k_prep<<<2048, 256, 0, stream>>>(W_up, W_down, W_hh, Wt_down, b_ih, b_hh,
                                   Wup_b, Wdn_b, Wfull_b, Wtd_b, bcomb, xcat0, tstep);
  k_fold<<<3330, 256, 0, stream>>>(W_ih, W_vt, inputs0, W_prob, Wfull_b, g0add, wpc);
  k_lat  <<<128, 256, 0, stream>>>(latent, Wc, bc, latbuf);
  k_sinit<<<512, 256, 0, stream>>>(latbuf, Ws, bs, sinit);
  k_h0c0 <<<512, 256, 0, stream>>>(sinit, Wh, bh, Wcc, bcc, cbuf, xcat0);

  for (int r = 0; r < 16; ++r) {
    u16* xc = (r & 1) ? xcat1 : xcat0;
    u16* xn = (r & 1) ? xcat0 : xcat1;
    k_lstm <<<256, 256, 0, stream>>>(xc, Wfull_b, bcomb, cbuf, xn,
                                     r == 0 ? g0add : (const float*)nullptr);
    k_pgemm<<<512, 256, 0, stream>>>(xn, Wup_b, b_up, gumbel + (size_t)r * B * N,
                                     sbuf, stat_m, stat_l,
                                     Wtd_b, bt_down, Wt_pred, drop_u + (size_t)r * B * HT, t0buf);
    k_vhg  <<<512, 256, 0, stream>>>(sbuf, stat_m, stat_l, Wdn_b, out, HgPart, r);
    k_hgred<<<128, 256, 0, stream>>>(HgPart, t0buf, tstep, Wt_up, bt_up, out + TS_OFF,
                                     xn, Hgf, r);
  }
  k_prob<<<1, 256, 0, stream>>>(Hgf, tstep, Wt_up, bt_up, wpc, out + PROB_OFF);
}

// Round 3
// 1620.281 us; speedup vs baseline: 1.4474x; 1.2006x over previous
//
#include <hip/hip_runtime.h>

typedef float  __attribute__((ext_vector_type(4))) f32x4;
typedef int    __attribute__((ext_vector_type(4))) i32x4;
typedef unsigned short u16;

#define B    256
#define H    512
#define HIN  128
#define N    16384
#define RW   16
#define HT   32
#define KC2  672          // 160 (Hg|Ht) + 512 (h)
#define HOFF 160
#define RWN  262144       // RW*N
#define TS_OFF   67108864 // B*RW*N
#define PROB_OFF 67112960 // TS_OFF + B*RW

// ---------- helpers ----------
__device__ __forceinline__ u16 f2bf(float f) {
  unsigned u = __builtin_bit_cast(unsigned, f);
  u += 0x7FFFu + ((u >> 16) & 1u);         // RTNE
  return (u16)(u >> 16);
}
__device__ __forceinline__ float sigm(float x) { return 1.0f / (1.0f + expf(-x)); }

// no-nop MFMA: safe when A/B frags come from memory loads (waitcnt covers them)
__device__ __forceinline__ void mfma(f32x4& d, i32x4 a, i32x4 b) {
  asm volatile("v_mfma_f32_16x16x32_bf16 %0, %1, %2, %0" : "+v"(d) : "v"(a), "v"(b));
}
// nop MFMA: covers VALU-write -> MFMA-read hazard (acc init, f2bf-packed A)
__device__ __forceinline__ void mfma_n(f32x4& d, i32x4 a, i32x4 b) {
  asm volatile("s_nop 1\n\tv_mfma_f32_16x16x32_bf16 %0, %1, %2, %0" : "+v"(d) : "v"(a), "v"(b));
}
// MFMA-write -> VALU-read guard
__device__ __forceinline__ void fence_acc(f32x4& v) {
  asm volatile("s_nop 7\n\ts_nop 7" : "+v"(v));
}

// ---------- prologue ----------
__global__ __launch_bounds__(256) void k_prep(
    const float* __restrict__ W_up, const float* __restrict__ W_down,
    const float* __restrict__ W_hh, const float* __restrict__ Wt_down,
    const float* __restrict__ b_ih, const float* __restrict__ b_hh,
    const float* __restrict__ Wh, const float* __restrict__ Wcc,
    u16* __restrict__ Wup_b, u16* __restrict__ Wdn_b, u16* __restrict__ Wfull,
    u16* __restrict__ Wtd_b, u16* __restrict__ Whc_b,
    float* __restrict__ bcomb, u16* __restrict__ xcat0, float* __restrict__ tstep)
{
  const int idx0 = blockIdx.x * 256 + threadIdx.x;
  const int stride = gridDim.x * 256;
  for (int i = idx0; i < N * H; i += stride) Wup_b[i] = f2bf(W_up[i]);
  for (int i = idx0; i < HIN * N; i += stride) Wdn_b[i] = f2bf(W_down[i]);
  for (int i = idx0; i < 4 * H * H; i += stride) {
    int j = i >> 9, k = i & 511;
    Wfull[j * KC2 + HOFF + k] = f2bf(W_hh[i]);
  }
  for (int i = idx0; i < HT * H; i += stride) Wtd_b[i] = f2bf(Wt_down[i]);
  for (int i = idx0; i < 2 * H * H; i += stride) {
    int j = i >> 9, k = i & 511;
    Whc_b[i] = f2bf(j < H ? Wh[j * H + k] : Wcc[(j - H) * H + k]);
  }
  for (int i = idx0; i < 4 * H; i += stride) bcomb[i] = b_ih[i] + b_hh[i];
  for (int i = idx0; i < B * HOFF; i += stride) {
    int b = i / HOFF, m = i - b * HOFF;
    xcat0[b * KC2 + m] = 0;
  }
  for (int i = idx0; i < B; i += stride) tstep[i] = 0.0f;
}

// Wcomb = W_ih @ W_vt into Wfull cols 0..159; g0add = inputs0 @ W_ih^T; wpc = W_prob @ W_vt
__global__ __launch_bounds__(256) void k_fold(
    const float* __restrict__ W_ih, const float* __restrict__ W_vt,
    const float* __restrict__ inputs0, const float* __restrict__ W_prob,
    u16* __restrict__ Wfull, float* __restrict__ g0add, float* __restrict__ wpc)
{
  int idx = blockIdx.x * 256 + threadIdx.x;
  if (idx < 2048 * 160) {
    int j = idx / 160, m = idx - j * 160;
    float a = 0.0f;
    for (int c = 0; c < HIN; ++c) a += W_ih[j * HIN + c] * W_vt[c * 160 + m];
    Wfull[j * KC2 + m] = f2bf(a);
  } else if (idx < 2048 * 160 + 256 * 2048) {
    int i2 = idx - 2048 * 160;
    int b = i2 >> 11, j = i2 & 2047;
    float a = 0.0f;
    for (int k = 0; k < HIN; ++k) a += inputs0[b * HIN + k] * W_ih[j * HIN + k];
    g0add[i2] = a;
  } else if (idx < 2048 * 160 + 256 * 2048 + 160) {
    int m = idx - (2048 * 160 + 256 * 2048);
    float a = 0.0f;
    for (int k = 0; k < HIN; ++k) a += W_prob[k] * W_vt[k * 160 + m];
    wpc[m] = a;
  }
}

__global__ __launch_bounds__(256) void k_lat(
    const float* __restrict__ latent, const float* __restrict__ Wc,
    const float* __restrict__ bc, float* __restrict__ latbuf)
{
  int idx = blockIdx.x * 256 + threadIdx.x;       // 256*128
  int b = idx >> 7, i = idx & 127;
  float acc = bc[i];
  for (int k = 0; k < 129; ++k) acc += latent[b * 129 + k] * Wc[i * 129 + k];
  latbuf[idx] = tanhf(acc);
}

__global__ __launch_bounds__(256) void k_sinit(
    const float* __restrict__ latbuf, const float* __restrict__ Ws,
    const float* __restrict__ bs, u16* __restrict__ sinit_b)
{
  int idx = blockIdx.x * 256 + threadIdx.x;       // 256*512
  int b = idx >> 9, j = idx & 511;
  float acc = bs[j];
  for (int k = 0; k < HIN; ++k) acc += latbuf[b * HIN + k] * Ws[j * HIN + k];
  sinit_b[idx] = f2bf(tanhf(acc));
}

// h0/c0 via MFMA: out[256][1024] = tanh(sinit @ [Wh;Wcc]^T + [bh;bcc])
// grid 1024 = 16 rb(16 rows) x 64 cb(16 cols); 4 waves split K (128 each).
__global__ __launch_bounds__(256) void k_h0c0m(
    const u16* __restrict__ sinit_b, const u16* __restrict__ Whc_b,
    const float* __restrict__ bh, const float* __restrict__ bcc,
    float* __restrict__ cbuf, u16* __restrict__ xc0)
{
  const int rb = blockIdx.x >> 6, cb = blockIdx.x & 63;
  const int wave = threadIdx.x >> 6, lane = threadIdx.x & 63;
  const int lr = lane & 15, lk = lane >> 4;
  const int m0 = rb * 16, col0 = cb * 16;
  const u16* ab = sinit_b + (m0 + lr) * H + wave * 128 + 8 * lk;
  const u16* bb = Whc_b + (col0 + lr) * H + wave * 128 + 8 * lk;
  f32x4 acc[2] = {};
  mfma_n(acc[0], *(const i32x4*)(ab),      *(const i32x4*)(bb));
  mfma_n(acc[1], *(const i32x4*)(ab + 32), *(const i32x4*)(bb + 32));
  mfma(acc[0], *(const i32x4*)(ab + 64), *(const i32x4*)(bb + 64));
  mfma(acc[1], *(const i32x4*)(ab + 96), *(const i32x4*)(bb + 96));
  fence_acc(acc[0]); fence_acc(acc[1]);
  __shared__ float q[4][16][17];
  #pragma unroll
  for (int rr = 0; rr < 4; ++rr)
    q[wave][4 * lk + rr][lr] = acc[0][rr] + acc[1][rr];
  __syncthreads();
  const int r2 = threadIdx.x >> 4, jj = threadIdx.x & 15;
  float s = q[0][r2][jj] + q[1][r2][jj] + q[2][r2][jj] + q[3][r2][jj];
  int col = col0 + jj;
  if (col < H) xc0[(m0 + r2) * KC2 + HOFF + col] = f2bf(tanhf(s + bh[col]));
  else         cbuf[(m0 + r2) * H + col - H]     = tanhf(s + bcc[col - H]);
}

// ---------- per-step K1: gates GEMM (K=672 fused [Hg|Ht|h]) + LSTM pointwise ----------
// grid 512 = 16 rb(16 rows) x 32 cb(16 cols/gate); wave = gate quadrant.
__global__ __launch_bounds__(256) void k_lstm(
    const u16* __restrict__ xc, const u16* __restrict__ Wfull,
    const float* __restrict__ bcomb, float* __restrict__ cbuf,
    u16* __restrict__ xn, const float* __restrict__ g0)
{
  const int rb = blockIdx.x >> 5, cb = blockIdx.x & 31;
  const int wave = threadIdx.x >> 6, lane = threadIdx.x & 63;
  const int lr = lane & 15, lk = lane >> 4;
  const int m0 = rb * 16, j0 = cb * 16;
  const int gcol = wave * H + j0 + lr;
  f32x4 acc[2] = {};
  const u16* brow = Wfull + gcol * KC2 + 8 * lk;
  const u16* arow = xc + (m0 + lr) * KC2 + 8 * lk;
  mfma_n(acc[0], *(const i32x4*)(arow),      *(const i32x4*)(brow));
  mfma_n(acc[1], *(const i32x4*)(arow + 32), *(const i32x4*)(brow + 32));
  #pragma unroll 4
  for (int i = 2; i < 21; ++i) {
    int kk = i * 32;
    mfma(acc[i & 1], *(const i32x4*)(arow + kk), *(const i32x4*)(brow + kk));
  }
  fence_acc(acc[0]); fence_acc(acc[1]);
  __shared__ float q[4][16][17];
  float bias = bcomb[gcol];
  #pragma unroll
  for (int rr = 0; rr < 4; ++rr)
    q[wave][4 * lk + rr][lr] = acc[0][rr] + acc[1][rr] + bias;
  __syncthreads();
  const int r2 = threadIdx.x >> 4, jj = threadIdx.x & 15;
  const int b = m0 + r2, j = j0 + jj;
  float gi = q[0][r2][jj], gf = q[1][r2][jj], gg = q[2][r2][jj], go = q[3][r2][jj];
  if (g0) {
    const float* gp = g0 + b * 2048 + j;
    gi += gp[0]; gf += gp[512]; gg += gp[1024]; go += gp[1536];
  }
  float c  = cbuf[b * H + j];
  float c2 = sigm(gf) * c + sigm(gi) * tanhf(gg);
  float h2 = sigm(go) * tanhf(c2);
  cbuf[b * H + j] = c2;
  xn[b * KC2 + HOFF + j] = f2bf(h2);
}

// ---------- per-step K2: p GEMM + gumbel + per-block softmax stats + td/t0 straggler ----------
// grid 1024 = 8 rb(32 rows) x 128 cb(128 cols); wave covers 32 cols.
__global__ __launch_bounds__(256) void k_pgemm(
    const u16* __restrict__ xn, const u16* __restrict__ Wup,
    const float* __restrict__ b_up, const float* __restrict__ gum,
    float* __restrict__ sbuf, float* __restrict__ stat_m, float* __restrict__ stat_l,
    const u16* __restrict__ Wtd, const float* __restrict__ bt_down,
    const float* __restrict__ Wt_pred, const float* __restrict__ du,
    float* __restrict__ t0)
{
  const int rb = blockIdx.x >> 7, cb = blockIdx.x & 127;
  const int wave = threadIdx.x >> 6, lane = threadIdx.x & 63;
  const int lr = lane & 15, lk = lane >> 4;
  const int m0 = rb * 32;
  const int n0 = cb * 128 + wave * 32;

  // prefetch gumbel + bias early: HBM latency hides under the K-loop MFMAs
  float gv[2][4][2], bup0 = b_up[n0 + lr], bup1 = b_up[n0 + 16 + lr];
  #pragma unroll
  for (int mi = 0; mi < 2; ++mi)
    #pragma unroll
    for (int rr = 0; rr < 4; ++rr) {
      int row = m0 + 16 * mi + 4 * lk + rr;
      gv[mi][rr][0] = gum[(size_t)row * N + n0 + lr];
      gv[mi][rr][1] = gum[(size_t)row * N + n0 + 16 + lr];
    }

  f32x4 acc[2][2] = {};
  const u16* a0 = xn + (m0 + lr) * KC2 + HOFF + 8 * lk;
  const u16* a1 = a0 + 16 * KC2;
  const u16* b0 = Wup + (n0 + lr) * H + 8 * lk;
  const u16* b1 = b0 + 16 * H;
  {
    i32x4 af0 = *(const i32x4*)(a0);
    i32x4 af1 = *(const i32x4*)(a1);
    i32x4 bf0 = *(const i32x4*)(b0);
    i32x4 bf1 = *(const i32x4*)(b1);
    mfma_n(acc[0][0], af0, bf0); mfma_n(acc[0][1], af0, bf1);
    mfma_n(acc[1][0], af1, bf0); mfma_n(acc[1][1], af1, bf1);
  }
  #pragma unroll 3
  for (int kk = 32; kk < H; kk += 32) {
    i32x4 af0 = *(const i32x4*)(a0 + kk);
    i32x4 af1 = *(const i32x4*)(a1 + kk);
    i32x4 bf0 = *(const i32x4*)(b0 + kk);
    i32x4 bf1 = *(const i32x4*)(b1 + kk);
    mfma(acc[0][0], af0, bf0); mfma(acc[0][1], af0, bf1);
    mfma(acc[1][0], af1, bf0); mfma(acc[1][1], af1, bf1);
  }
  #pragma unroll
  for (int mi = 0; mi < 2; ++mi) { fence_acc(acc[mi][0]); fence_acc(acc[mi][1]); }

  __shared__ float sm[4][32], sl[4][32];
  #pragma unroll
  for (int mi = 0; mi < 2; ++mi)
    #pragma unroll
    for (int rr = 0; rr < 4; ++rr) {
      int rl = 16 * mi + 4 * lk + rr;
      int row = m0 + rl;
      float* sp = sbuf + (size_t)row * N + n0 + lr;
      float v0 = acc[mi][0][rr] + bup0 + gv[mi][rr][0];
      float v1 = acc[mi][1][rr] + bup1 + gv[mi][rr][1];
      sp[0] = v0; sp[16] = v1;
      float vm = fmaxf(v0, v1);
      #pragma unroll
      for (int off = 1; off < 16; off <<= 1) vm = fmaxf(vm, __shfl_xor(vm, off));
      float e = expf(v0 - vm) + expf(v1 - vm);
      #pragma unroll
      for (int off = 1; off < 16; off <<= 1) e += __shfl_xor(e, off);
      if (lr == 0) { sm[wave][rl] = vm; sl[wave][rl] = e; }
    }
  __syncthreads();
  if (threadIdx.x < 32) {
    float m = sm[0][threadIdx.x], l = sl[0][threadIdx.x];
    #pragma unroll
    for (int w = 1; w < 4; ++w) {
      float mc = sm[w][threadIdx.x], lc = sl[w][threadIdx.x];
      if (mc > m) { l = l * expf(m - mc) + lc; m = mc; }
      else        { l += lc * expf(mc - m); }
    }
    stat_m[cb * B + m0 + threadIdx.x] = m;
    stat_l[cb * B + m0 + threadIdx.x] = l;
  }

  // straggler: td = tanh(h2 @ Wt_down^T + bt)*mask/keep ; t0 = min(td @ Wt_pred^T, 1)
  if (cb == 0 && wave < 2) {
    f32x4 acc2[2] = {};
    const u16* at = xn + (m0 + wave * 16 + lr) * KC2 + HOFF + 8 * lk;
    {
      i32x4 af = *(const i32x4*)(at);
      mfma_n(acc2[0], af, *(const i32x4*)(Wtd + lr * H + 8 * lk));
      mfma_n(acc2[1], af, *(const i32x4*)(Wtd + (16 + lr) * H + 8 * lk));
    }
    for (int kk = 32; kk < H; kk += 32) {
      i32x4 af = *(const i32x4*)(at + kk);
      mfma(acc2[0], af, *(const i32x4*)(Wtd + lr * H + kk + 8 * lk));
      mfma(acc2[1], af, *(const i32x4*)(Wtd + (16 + lr) * H + kk + 8 * lk));
    }
    fence_acc(acc2[0]); fence_acc(acc2[1]);
    float wp0 = Wt_pred[lr],  wp1 = Wt_pred[16 + lr];
    float bt0 = bt_down[lr],  bt1 = bt_down[16 + lr];
    #pragma unroll
    for (int rr = 0; rr < 4; ++rr) {
      int row = m0 + wave * 16 + 4 * lk + rr;
      float td0 = tanhf(acc2[0][rr] + bt0);
      float td1 = tanhf(acc2[1][rr] + bt1);
      td0 = (du[row * HT + lr]      < 0.8f) ? td0 * 1.25f : 0.0f;
      td1 = (du[row * HT + 16 + lr] < 0.8f) ? td1 * 1.25f : 0.0f;
      float part = td0 * wp0 + td1 * wp1;
      #pragma unroll
      for (int off = 1; off < 16; off <<= 1) part += __shfl_xor(part, off);
      if (lr == 0) t0[row] = fminf(part, 1.0f);
    }
  }
}

// ---------- per-step K3: stat merge + v write + Hg split-K partials ----------
// grid 2048 = 16 rb(16 rows) x 128 cb(128 cols); waves split HIN (32 Hg-cols each).
__global__ __launch_bounds__(256) void k_vhg(
    const float* __restrict__ sbuf, const float* __restrict__ stat_m,
    const float* __restrict__ stat_l, const u16* __restrict__ Wdn,
    float* __restrict__ out_rw, float* __restrict__ HgPart, int r)
{
  const int rb = blockIdx.x >> 7, cb = blockIdx.x & 127;
  const int tid = threadIdx.x;
  const int wave = tid >> 6, lane = tid & 63;
  const int lr = lane & 15, lk = lane >> 4;
  const int m0 = rb * 16;
  const int nb = cb * 128;

  // parallel softmax-stat merge over 128 chunks: 16 parts x 8 chunks, then 16-deep serial
  __shared__ float mP[16][17], lP[16][17], rowM_s[16], rowR_s[16];
  {
    int row = tid & 15, part = tid >> 4;
    float m = -3.0e38f, l = 0.0f;
    for (int c = part * 8; c < part * 8 + 8; ++c) {
      float mc = stat_m[c * B + m0 + row], lc = stat_l[c * B + m0 + row];
      if (mc > m) { l = l * expf(m - mc) + lc; m = mc; }
      else        { l += lc * expf(mc - m); }
    }
    mP[part][row] = m; lP[part][row] = l;
  }
  __syncthreads();
  if (tid < 16) {
    float m = mP[0][tid], l = lP[0][tid];
    for (int p2 = 1; p2 < 16; ++p2) {
      float mc = mP[p2][tid], lc = lP[p2][tid];
      if (mc > m) { l = l * expf(m - mc) + lc; m = mc; }
      else        { l += lc * expf(mc - m); }
    }
    rowM_s[tid] = m; rowR_s[tid] = 1.0f / l;
  }
  __syncthreads();

  const float M = rowM_s[lr], R = rowR_s[lr];
  const float* srow = sbuf + (size_t)(m0 + lr) * N + nb + 8 * lk;
  float* orow = out_rw + (size_t)(m0 + lr) * RWN + r * N + nb + 8 * lk;
  f32x4 acc[2] = {};
  #pragma unroll
  for (int kk = 0; kk < 4; ++kk) {
    f32x4 s0 = *(const f32x4*)(srow + kk * 32);
    f32x4 s1 = *(const f32x4*)(srow + kk * 32 + 4);
    f32x4 w0, w1;
    #pragma unroll
    for (int e = 0; e < 4; ++e) { w0[e] = expf(s0[e] - M) * R; w1[e] = expf(s1[e] - M) * R; }
    if (wave == 0) {
      *(f32x4*)(orow + kk * 32) = w0;
      *(f32x4*)(orow + kk * 32 + 4) = w1;
    }
    i32x4 a;
    a[0] = (int)f2bf(w0[0]) | ((int)f2bf(w0[1]) << 16);
    a[1] = (int)f2bf(w0[2]) | ((int)f2bf(w0[3]) << 16);
    a[2] = (int)f2bf(w1[0]) | ((int)f2bf(w1[1]) << 16);
    a[3] = (int)f2bf(w1[2]) | ((int)f2bf(w1[3]) << 16);
    #pragma unroll
    for (int ni = 0; ni < 2; ++ni) {
      i32x4 bf = *(const i32x4*)(Wdn + (size_t)(wave * 32 + 16 * ni + lr) * N + nb + kk * 32 + 8 * lk);
      mfma_n(acc[ni], a, bf);
    }
  }
  fence_acc(acc[0]); fence_acc(acc[1]);
  float* hp = HgPart + (size_t)cb * (B * HIN);
  #pragma unroll
  for (int ni = 0; ni < 2; ++ni)
    #pragma unroll
    for (int rr = 0; rr < 4; ++rr)
      hp[(m0 + 4 * lk + rr) * HIN + wave * 32 + 16 * ni + lr] = acc[ni][rr];
}

// ---------- per-step K4: parallel Hg reduce + t constraints + Ht/ts writes ----------
// grid 128 x 256 threads; each thread one (b,c) of Hg; each block owns 2 batch rows.
__global__ __launch_bounds__(256) void k_hgred(
    const float* __restrict__ HgPart, const float* __restrict__ t0,
    float* __restrict__ tstep, const float* __restrict__ Wt_up,
    const float* __restrict__ bt_up, float* __restrict__ ts_out,
    u16* __restrict__ xn, float* __restrict__ Hgf, int r)
{
  const int tid = threadIdx.x;
  const int idx = blockIdx.x * 256 + tid;
  float s0 = 0.f, s1 = 0.f, s2 = 0.f, s3 = 0.f;
  #pragma unroll 4
  for (int c = 0; c < 128; c += 4) {
    s0 += HgPart[(size_t)(c + 0) * (B * HIN) + idx];
    s1 += HgPart[(size_t)(c + 1) * (B * HIN) + idx];
    s2 += HgPart[(size_t)(c + 2) * (B * HIN) + idx];
    s3 += HgPart[(size_t)(c + 3) * (B * HIN) + idx];
  }
  float hg = (s0 + s1) + (s2 + s3);

  __shared__ float red[256], tl[256];
  float tv = t0[tid];
  red[tid] = tv; __syncthreads();
  for (int s = 128; s > 0; s >>= 1) {
    if (tid < s) red[tid] = fminf(red[tid], red[tid + s]);
    __syncthreads();
  }
  float mn = red[0]; __syncthreads();
  if (mn < 0.1f) tv -= mn;
  red[tid] = tv; __syncthreads();
  for (int s = 128; s > 0; s >>= 1) {
    if (tid < s) red[tid] = fmaxf(red[tid], red[tid + s]);
    __syncthreads();
  }
  float mx = red[0];
  if (mx > 1.0f) tv /= mx;
  tv = fminf(fmaxf(tv, tstep[r * B + tid]), 1.0f);
  tl[tid] = tv; __syncthreads();

  int b = idx >> 7, c = idx & 127;
  xn[b * KC2 + c] = f2bf(hg);
  Hgf[idx] = hg;
  const int b0 = blockIdx.x * 2;
  if (tid < 64) {
    int bb = b0 + (tid >> 5), j = tid & 31;
    xn[bb * KC2 + HIN + j] = f2bf(tl[bb] * Wt_up[j] + bt_up[j]);
  }
  if (tid < 2) {
    int bb = b0 + tid;
    tstep[(r + 1) * B + bb] = tl[bb];
    ts_out[bb * RW + r] = tl[bb];
  }
}

__global__ __launch_bounds__(256) void k_prob(
    const float* __restrict__ Hgf, const float* __restrict__ tstep,
    const float* __restrict__ Wt_up, const float* __restrict__ bt_up,
    const float* __restrict__ wpc, float* __restrict__ outp)
{
  int b = threadIdx.x;
  float acc = 0.0f;
  for (int m = 0; m < HIN; ++m) acc += Hgf[b * HIN + m] * wpc[m];
  float tv = tstep[16 * B + b];
  for (int j = 0; j < HT; ++j) acc += (tv * Wt_up[j] + bt_up[j]) * wpc[HIN + j];
  outp[b] = acc;
}

// ---------- launch ----------
extern "C" void kernel_launch(void* const* d_in, const int* in_sizes, int n_in,
                              void* d_out, int out_size, void* d_ws, size_t ws_size,
                              hipStream_t stream) {
  (void)in_sizes; (void)n_in; (void)out_size; (void)ws_size;
  const float* latent  = (const float*)d_in[0];
  const float* inputs0 = (const float*)d_in[1];
  const float* Wc      = (const float*)d_in[2];
  const float* bc      = (const float*)d_in[3];
  const float* Ws      = (const float*)d_in[4];
  const float* bs      = (const float*)d_in[5];
  const float* Wh      = (const float*)d_in[6];
  const float* bh      = (const float*)d_in[7];
  const float* Wcc     = (const float*)d_in[8];
  const float* bcc     = (const float*)d_in[9];
  const float* W_ih    = (const float*)d_in[10];
  const float* b_ih    = (const float*)d_in[11];
  const float* W_hh    = (const float*)d_in[12];
  const float* b_hh    = (const float*)d_in[13];
  const float* W_up    = (const float*)d_in[14];
  const float* b_up    = (const float*)d_in[15];
  const float* W_down  = (const float*)d_in[16];
  const float* Wt_down = (const float*)d_in[17];
  const float* bt_down = (const float*)d_in[18];
  const float* Wt_pred = (const float*)d_in[19];
  const float* Wt_up   = (const float*)d_in[20];
  const float* bt_up   = (const float*)d_in[21];
  const float* W_vt    = (const float*)d_in[22];
  const float* W_prob  = (const float*)d_in[23];
  const float* gumbel  = (const float*)d_in[24];
  const float* drop_u  = (const float*)d_in[25];
  float* out = (float*)d_out;

  char* p = (char*)d_ws;
  auto alloc = [&](size_t bytes) { char* r = p; p += (bytes + 255) & ~(size_t)255; return r; };
  u16*   Wup_b  = (u16*)  alloc((size_t)N * H * 2);
  u16*   Wdn_b  = (u16*)  alloc((size_t)HIN * N * 2);
  u16*   Wfull_b= (u16*)  alloc((size_t)4 * H * KC2 * 2);
  u16*   Wtd_b  = (u16*)  alloc((size_t)HT * H * 2);
  u16*   Whc_b  = (u16*)  alloc((size_t)2 * H * H * 2);
  float* bcomb  = (float*)alloc(4 * H * 4);
  u16*   xcat0  = (u16*)  alloc((size_t)B * KC2 * 2);
  u16*   xcat1  = (u16*)  alloc((size_t)B * KC2 * 2);
  float* cbuf   = (float*)alloc((size_t)B * H * 4);
  u16*   sinit_b= (u16*)  alloc((size_t)B * H * 2);
  float* latbuf = (float*)alloc((size_t)B * HIN * 4);
  float* sbuf   = (float*)alloc((size_t)B * N * 4);
  float* stat_m = (float*)alloc((size_t)128 * B * 4);
  float* stat_l = (float*)alloc((size_t)128 * B * 4);
  float* t0buf  = (float*)alloc(B * 4);
  float* tstep  = (float*)alloc((size_t)17 * B * 4);
  float* HgPart = (float*)alloc((size_t)128 * B * HIN * 4);
  float* Hgf    = (float*)alloc((size_t)B * HIN * 4);
  float* g0add  = (float*)alloc((size_t)B * 4 * H * 4);
  float* wpc    = (float*)alloc(160 * 4);

  k_prep<<<2048, 256, 0, stream>>>(W_up, W_down, W_hh, Wt_down, b_ih, b_hh, Wh, Wcc,
                                   Wup_b, Wdn_b, Wfull_b, Wtd_b, Whc_b, bcomb, xcat0, tstep);
  k_fold<<<3330, 256, 0, stream>>>(W_ih, W_vt, inputs0, W_prob, Wfull_b, g0add, wpc);
  k_lat  <<<128, 256, 0, stream>>>(latent, Wc, bc, latbuf);
  k_sinit<<<512, 256, 0, stream>>>(latbuf, Ws, bs, sinit_b);
  k_h0c0m<<<1024, 256, 0, stream>>>(sinit_b, Whc_b, bh, bcc, cbuf, xcat0);

  for (int r = 0; r < 16; ++r) {
    u16* xc = (r & 1) ? xcat1 : xcat0;
    u16* xn = (r & 1) ? xcat0 : xcat1;
    k_lstm <<<512, 256, 0, stream>>>(xc, Wfull_b, bcomb, cbuf, xn,
                                     r == 0 ? g0add : (const float*)nullptr);
    k_pgemm<<<1024, 256, 0, stream>>>(xn, Wup_b, b_up, gumbel + (size_t)r * B * N,
                                      sbuf, stat_m, stat_l,
                                      Wtd_b, bt_down, Wt_pred, drop_u + (size_t)r * B * HT, t0buf);
    k_vhg  <<<2048, 256, 0, stream>>>(sbuf, stat_m, stat_l, Wdn_b, out, HgPart, r);
    k_hgred<<<128, 256, 0, stream>>>(HgPart, t0buf, tstep, Wt_up, bt_up, out + TS_OFF,
                                     xn, Hgf, r);
  }
  k_prob<<<1, 256, 0, stream>>>(Hgf, tstep, Wt_up, bt_up, wpc, out + PROB_OFF);
}

// Round 4
// 1293.569 us; speedup vs baseline: 1.8130x; 1.2526x over previous
//
#include <hip/hip_runtime.h>

typedef float  __attribute__((ext_vector_type(4))) f32x4;
typedef int    __attribute__((ext_vector_type(4))) i32x4;
typedef unsigned short u16;

#define B    256
#define H    512
#define HIN  128
#define N    16384
#define RW   16
#define HT   32
#define KC2  672          // 160 (Hg|Ht) + 512 (h)
#define HOFF 160
#define RWN  262144       // RW*N
#define TS_OFF   67108864 // B*RW*N
#define PROB_OFF 67112960 // TS_OFF + B*RW

// ---------- helpers ----------
__device__ __forceinline__ u16 f2bf(float f) {
  unsigned u = __builtin_bit_cast(unsigned, f);
  u += 0x7FFFu + ((u >> 16) & 1u);         // RTNE
  return (u16)(u >> 16);
}
__device__ __forceinline__ float bf2f(u16 v) {
  return __builtin_bit_cast(float, ((unsigned)v) << 16);
}
__device__ __forceinline__ float sigm(float x) { return 1.0f / (1.0f + expf(-x)); }

// no-nop MFMA: safe when A/B frags come from memory loads (waitcnt covers them)
__device__ __forceinline__ void mfma(f32x4& d, i32x4 a, i32x4 b) {
  asm volatile("v_mfma_f32_16x16x32_bf16 %0, %1, %2, %0" : "+v"(d) : "v"(a), "v"(b));
}
// nop MFMA: covers VALU-write -> MFMA-read hazard (acc init, f2bf-packed A)
__device__ __forceinline__ void mfma_n(f32x4& d, i32x4 a, i32x4 b) {
  asm volatile("s_nop 1\n\tv_mfma_f32_16x16x32_bf16 %0, %1, %2, %0" : "+v"(d) : "v"(a), "v"(b));
}
// MFMA-write -> VALU-read guard
__device__ __forceinline__ void fence_acc(f32x4& v) {
  asm volatile("s_nop 7\n\ts_nop 7" : "+v"(v));
}

// ---------- prologue ----------
__global__ __launch_bounds__(256) void k_prep(
    const float* __restrict__ W_up, const float* __restrict__ W_down,
    const float* __restrict__ W_hh, const float* __restrict__ Wt_down,
    const float* __restrict__ b_ih, const float* __restrict__ b_hh,
    const float* __restrict__ Wh, const float* __restrict__ Wcc,
    u16* __restrict__ Wup_b, u16* __restrict__ Wdn_b, u16* __restrict__ Wfull,
    u16* __restrict__ Wtd_b, u16* __restrict__ Whc_b,
    float* __restrict__ bcomb, u16* __restrict__ xcat0, float* __restrict__ tstep)
{
  const int idx0 = blockIdx.x * 256 + threadIdx.x;
  const int stride = gridDim.x * 256;
  for (int i = idx0; i < N * H; i += stride) Wup_b[i] = f2bf(W_up[i]);
  for (int i = idx0; i < HIN * N; i += stride) Wdn_b[i] = f2bf(W_down[i]);
  for (int i = idx0; i < 4 * H * H; i += stride) {
    int j = i >> 9, k = i & 511;
    Wfull[j * KC2 + HOFF + k] = f2bf(W_hh[i]);
  }
  for (int i = idx0; i < HT * H; i += stride) Wtd_b[i] = f2bf(Wt_down[i]);
  for (int i = idx0; i < 2 * H * H; i += stride) {
    int j = i >> 9, k = i & 511;
    Whc_b[i] = f2bf(j < H ? Wh[j * H + k] : Wcc[(j - H) * H + k]);
  }
  for (int i = idx0; i < 4 * H; i += stride) bcomb[i] = b_ih[i] + b_hh[i];
  for (int i = idx0; i < B * HOFF; i += stride) {
    int b = i / HOFF, m = i - b * HOFF;
    xcat0[b * KC2 + m] = 0;
  }
  for (int i = idx0; i < B; i += stride) tstep[i] = 0.0f;
}

// Wcomb = W_ih @ W_vt into Wfull cols 0..159; g0add = inputs0 @ W_ih^T; wpc = W_prob @ W_vt
__global__ __launch_bounds__(256) void k_fold(
    const float* __restrict__ W_ih, const float* __restrict__ W_vt,
    const float* __restrict__ inputs0, const float* __restrict__ W_prob,
    u16* __restrict__ Wfull, float* __restrict__ g0add, float* __restrict__ wpc)
{
  int idx = blockIdx.x * 256 + threadIdx.x;
  if (idx < 2048 * 160) {
    int j = idx / 160, m = idx - j * 160;
    float a = 0.0f;
    for (int c = 0; c < HIN; ++c) a += W_ih[j * HIN + c] * W_vt[c * 160 + m];
    Wfull[j * KC2 + m] = f2bf(a);
  } else if (idx < 2048 * 160 + 256 * 2048) {
    int i2 = idx - 2048 * 160;
    int b = i2 >> 11, j = i2 & 2047;
    float a = 0.0f;
    for (int k = 0; k < HIN; ++k) a += inputs0[b * HIN + k] * W_ih[j * HIN + k];
    g0add[i2] = a;
  } else if (idx < 2048 * 160 + 256 * 2048 + 160) {
    int m = idx - (2048 * 160 + 256 * 2048);
    float a = 0.0f;
    for (int k = 0; k < HIN; ++k) a += W_prob[k] * W_vt[k * 160 + m];
    wpc[m] = a;
  }
}

__global__ __launch_bounds__(256) void k_lat(
    const float* __restrict__ latent, const float* __restrict__ Wc,
    const float* __restrict__ bc, float* __restrict__ latbuf)
{
  int idx = blockIdx.x * 256 + threadIdx.x;       // 256*128
  int b = idx >> 7, i = idx & 127;
  float acc = bc[i];
  for (int k = 0; k < 129; ++k) acc += latent[b * 129 + k] * Wc[i * 129 + k];
  latbuf[idx] = tanhf(acc);
}

__global__ __launch_bounds__(256) void k_sinit(
    const float* __restrict__ latbuf, const float* __restrict__ Ws,
    const float* __restrict__ bs, u16* __restrict__ sinit_b)
{
  int idx = blockIdx.x * 256 + threadIdx.x;       // 256*512
  int b = idx >> 9, j = idx & 511;
  float acc = bs[j];
  for (int k = 0; k < HIN; ++k) acc += latbuf[b * HIN + k] * Ws[j * HIN + k];
  sinit_b[idx] = f2bf(tanhf(acc));
}

// h0/c0 via MFMA: out[256][1024] = tanh(sinit @ [Wh;Wcc]^T + [bh;bcc])
__global__ __launch_bounds__(256) void k_h0c0m(
    const u16* __restrict__ sinit_b, const u16* __restrict__ Whc_b,
    const float* __restrict__ bh, const float* __restrict__ bcc,
    float* __restrict__ cbuf, u16* __restrict__ xc0)
{
  const int rb = blockIdx.x >> 6, cb = blockIdx.x & 63;
  const int wave = threadIdx.x >> 6, lane = threadIdx.x & 63;
  const int lr = lane & 15, lk = lane >> 4;
  const int m0 = rb * 16, col0 = cb * 16;
  const u16* ab = sinit_b + (m0 + lr) * H + wave * 128 + 8 * lk;
  const u16* bb = Whc_b + (col0 + lr) * H + wave * 128 + 8 * lk;
  f32x4 acc[2] = {};
  mfma_n(acc[0], *(const i32x4*)(ab),      *(const i32x4*)(bb));
  mfma_n(acc[1], *(const i32x4*)(ab + 32), *(const i32x4*)(bb + 32));
  mfma(acc[0], *(const i32x4*)(ab + 64), *(const i32x4*)(bb + 64));
  mfma(acc[1], *(const i32x4*)(ab + 96), *(const i32x4*)(bb + 96));
  fence_acc(acc[0]); fence_acc(acc[1]);
  __shared__ float q[4][16][17];
  #pragma unroll
  for (int rr = 0; rr < 4; ++rr)
    q[wave][4 * lk + rr][lr] = acc[0][rr] + acc[1][rr];
  __syncthreads();
  const int r2 = threadIdx.x >> 4, jj = threadIdx.x & 15;
  float s = q[0][r2][jj] + q[1][r2][jj] + q[2][r2][jj] + q[3][r2][jj];
  int col = col0 + jj;
  if (col < H) xc0[(m0 + r2) * KC2 + HOFF + col] = f2bf(tanhf(s + bh[col]));
  else         cbuf[(m0 + r2) * H + col - H]     = tanhf(s + bcc[col - H]);
}

// ---------- per-step K1: gates GEMM + LSTM pointwise (+ rowL zero) ----------
__global__ __launch_bounds__(256) void k_lstm(
    const u16* __restrict__ xc, const u16* __restrict__ Wfull,
    const float* __restrict__ bcomb, float* __restrict__ cbuf,
    u16* __restrict__ xn, const float* __restrict__ g0, float* __restrict__ rowL)
{
  if (blockIdx.x == 0) rowL[threadIdx.x] = 0.0f;   // zero for this step's pgemm atomics
  const int rb = blockIdx.x >> 5, cb = blockIdx.x & 31;
  const int wave = threadIdx.x >> 6, lane = threadIdx.x & 63;
  const int lr = lane & 15, lk = lane >> 4;
  const int m0 = rb * 16, j0 = cb * 16;
  const int gcol = wave * H + j0 + lr;
  f32x4 acc[2] = {};
  const u16* brow = Wfull + gcol * KC2 + 8 * lk;
  const u16* arow = xc + (m0 + lr) * KC2 + 8 * lk;
  mfma_n(acc[0], *(const i32x4*)(arow),      *(const i32x4*)(brow));
  mfma_n(acc[1], *(const i32x4*)(arow + 32), *(const i32x4*)(brow + 32));
  #pragma unroll 4
  for (int i = 2; i < 21; ++i) {
    int kk = i * 32;
    mfma(acc[i & 1], *(const i32x4*)(arow + kk), *(const i32x4*)(brow + kk));
  }
  fence_acc(acc[0]); fence_acc(acc[1]);
  __shared__ float q[4][16][17];
  float bias = bcomb[gcol];
  #pragma unroll
  for (int rr = 0; rr < 4; ++rr)
    q[wave][4 * lk + rr][lr] = acc[0][rr] + acc[1][rr] + bias;
  __syncthreads();
  const int r2 = threadIdx.x >> 4, jj = threadIdx.x & 15;
  const int b = m0 + r2, j = j0 + jj;
  float gi = q[0][r2][jj], gf = q[1][r2][jj], gg = q[2][r2][jj], go = q[3][r2][jj];
  if (g0) {
    const float* gp = g0 + b * 2048 + j;
    gi += gp[0]; gf += gp[512]; gg += gp[1024]; go += gp[1536];
  }
  float c  = cbuf[b * H + j];
  float c2 = sigm(gf) * c + sigm(gi) * tanhf(gg);
  float h2 = sigm(go) * tanhf(c2);
  cbuf[b * H + j] = c2;
  xn[b * KC2 + HOFF + j] = f2bf(h2);
}

// ---------- per-step K2: p GEMM -> e=exp(p+g+b) (written to rw slot) ----------
//            + per-row e-sum atomics + Hg partial GEMM + td/t0 straggler
// grid 1024 = 8 rb(32 rows) x 128 cb(128 cols); wave covers 32 cols.
__global__ __launch_bounds__(256) void k_pgemm(
    const u16* __restrict__ xin, const u16* __restrict__ Wup,
    const float* __restrict__ b_up, const float* __restrict__ gum,
    float* __restrict__ out_rw, float* __restrict__ rowL,
    u16* __restrict__ HgPart, const u16* __restrict__ Wdn,
    const u16* __restrict__ Wtd, const float* __restrict__ bt_down,
    const float* __restrict__ Wt_pred, const float* __restrict__ du,
    float* __restrict__ t0, int r)
{
  const int rb = blockIdx.x >> 7, cb = blockIdx.x & 127;
  const int wave = threadIdx.x >> 6, lane = threadIdx.x & 63;
  const int lr = lane & 15, lk = lane >> 4;
  const int m0 = rb * 32;
  const int n0 = cb * 128 + wave * 32;

  // prefetch gumbel + bias early: HBM latency hides under the K-loop MFMAs
  float gv[2][4][2], bup0 = b_up[n0 + lr], bup1 = b_up[n0 + 16 + lr];
  #pragma unroll
  for (int mi = 0; mi < 2; ++mi)
    #pragma unroll
    for (int rr = 0; rr < 4; ++rr) {
      int row = m0 + 16 * mi + 4 * lk + rr;
      gv[mi][rr][0] = gum[(size_t)row * N + n0 + lr];
      gv[mi][rr][1] = gum[(size_t)row * N + n0 + 16 + lr];
    }

  f32x4 acc[2][2] = {};
  const u16* a0 = xin + (m0 + lr) * KC2 + HOFF + 8 * lk;
  const u16* a1 = a0 + 16 * KC2;
  const u16* b0 = Wup + (n0 + lr) * H + 8 * lk;
  const u16* b1 = b0 + 16 * H;
  {
    i32x4 af0 = *(const i32x4*)(a0);
    i32x4 af1 = *(const i32x4*)(a1);
    i32x4 bf0 = *(const i32x4*)(b0);
    i32x4 bf1 = *(const i32x4*)(b1);
    mfma_n(acc[0][0], af0, bf0); mfma_n(acc[0][1], af0, bf1);
    mfma_n(acc[1][0], af1, bf0); mfma_n(acc[1][1], af1, bf1);
  }
  #pragma unroll 3
  for (int kk = 32; kk < H; kk += 32) {
    i32x4 af0 = *(const i32x4*)(a0 + kk);
    i32x4 af1 = *(const i32x4*)(a1 + kk);
    i32x4 bf0 = *(const i32x4*)(b0 + kk);
    i32x4 bf1 = *(const i32x4*)(b1 + kk);
    mfma(acc[0][0], af0, bf0); mfma(acc[0][1], af0, bf1);
    mfma(acc[1][0], af1, bf0); mfma(acc[1][1], af1, bf1);
  }
  #pragma unroll
  for (int mi = 0; mi < 2; ++mi) { fence_acc(acc[mi][0]); fence_acc(acc[mi][1]); }

  __shared__ float eL[32][132];
  __shared__ float sL[4][32];
  #pragma unroll
  for (int mi = 0; mi < 2; ++mi)
    #pragma unroll
    for (int rr = 0; rr < 4; ++rr) {
      int rl = 16 * mi + 4 * lk + rr;
      int row = m0 + rl;
      float* sp = out_rw + (size_t)row * RWN + (size_t)r * N + n0 + lr;
      float v0 = acc[mi][0][rr] + bup0 + gv[mi][rr][0];
      float v1 = acc[mi][1][rr] + bup1 + gv[mi][rr][1];
      float e0 = expf(fminf(v0, 80.0f));
      float e1 = expf(fminf(v1, 80.0f));
      sp[0] = e0; sp[16] = e1;
      eL[rl][wave * 32 + lr] = e0;
      eL[rl][wave * 32 + 16 + lr] = e1;
      float par = e0 + e1;
      #pragma unroll
      for (int off = 1; off < 16; off <<= 1) par += __shfl_xor(par, off);
      if (lr == 0) sL[wave][rl] = par;
    }
  __syncthreads();
  if (threadIdx.x < 32)
    atomicAdd(rowL + m0 + threadIdx.x,
              sL[0][threadIdx.x] + sL[1][threadIdx.x] + sL[2][threadIdx.x] + sL[3][threadIdx.x]);

  // Hg partial GEMM: acc2[mi2][ni] += e(rows 32, K=128-slab) @ Wdn^T
  const int nb = cb * 128;
  f32x4 acc2[2][2] = {};
  #pragma unroll
  for (int kk2 = 0; kk2 < 4; ++kk2) {
    i32x4 af[2];
    #pragma unroll
    for (int mi2 = 0; mi2 < 2; ++mi2) {
      const float* ep = &eL[16 * mi2 + lr][kk2 * 32 + 8 * lk];
      f32x4 x0 = *(const f32x4*)ep;
      f32x4 x1 = *(const f32x4*)(ep + 4);
      af[mi2][0] = (int)f2bf(x0[0]) | ((int)f2bf(x0[1]) << 16);
      af[mi2][1] = (int)f2bf(x0[2]) | ((int)f2bf(x0[3]) << 16);
      af[mi2][2] = (int)f2bf(x1[0]) | ((int)f2bf(x1[1]) << 16);
      af[mi2][3] = (int)f2bf(x1[2]) | ((int)f2bf(x1[3]) << 16);
    }
    i32x4 bf0 = *(const i32x4*)(Wdn + (size_t)(wave * 32 + lr) * N + nb + kk2 * 32 + 8 * lk);
    i32x4 bf1 = *(const i32x4*)(Wdn + (size_t)(wave * 32 + 16 + lr) * N + nb + kk2 * 32 + 8 * lk);
    mfma_n(acc2[0][0], af[0], bf0); mfma_n(acc2[0][1], af[0], bf1);
    mfma_n(acc2[1][0], af[1], bf0); mfma_n(acc2[1][1], af[1], bf1);
  }
  #pragma unroll
  for (int mi2 = 0; mi2 < 2; ++mi2) { fence_acc(acc2[mi2][0]); fence_acc(acc2[mi2][1]); }
  u16* hp = HgPart + (size_t)cb * (B * HIN);
  #pragma unroll
  for (int mi2 = 0; mi2 < 2; ++mi2)
    #pragma unroll
    for (int ni = 0; ni < 2; ++ni)
      #pragma unroll
      for (int rr = 0; rr < 4; ++rr)
        hp[(m0 + 16 * mi2 + 4 * lk + rr) * HIN + wave * 32 + 16 * ni + lr] =
            f2bf(acc2[mi2][ni][rr]);

  // straggler: td = tanh(h2 @ Wt_down^T + bt)*mask/keep ; t0 = min(td @ Wt_pred^T, 1)
  if (cb == 0 && wave < 2) {
    f32x4 acc3[2] = {};
    const u16* at = xin + (m0 + wave * 16 + lr) * KC2 + HOFF + 8 * lk;
    {
      i32x4 af = *(const i32x4*)(at);
      mfma_n(acc3[0], af, *(const i32x4*)(Wtd + lr * H + 8 * lk));
      mfma_n(acc3[1], af, *(const i32x4*)(Wtd + (16 + lr) * H + 8 * lk));
    }
    for (int kk = 32; kk < H; kk += 32) {
      i32x4 af = *(const i32x4*)(at + kk);
      mfma(acc3[0], af, *(const i32x4*)(Wtd + lr * H + kk + 8 * lk));
      mfma(acc3[1], af, *(const i32x4*)(Wtd + (16 + lr) * H + kk + 8 * lk));
    }
    fence_acc(acc3[0]); fence_acc(acc3[1]);
    float wp0 = Wt_pred[lr],  wp1 = Wt_pred[16 + lr];
    float bt0 = bt_down[lr],  bt1 = bt_down[16 + lr];
    #pragma unroll
    for (int rr = 0; rr < 4; ++rr) {
      int row = m0 + wave * 16 + 4 * lk + rr;
      float td0 = tanhf(acc3[0][rr] + bt0);
      float td1 = tanhf(acc3[1][rr] + bt1);
      td0 = (du[row * HT + lr]      < 0.8f) ? td0 * 1.25f : 0.0f;
      td1 = (du[row * HT + 16 + lr] < 0.8f) ? td1 * 1.25f : 0.0f;
      float part = td0 * wp0 + td1 * wp1;
      #pragma unroll
      for (int off = 1; off < 16; off <<= 1) part += __shfl_xor(part, off);
      if (lr == 0) t0[row] = fminf(part, 1.0f);
    }
  }
}

// ---------- per-step K3: v = e/l in-place scale + Hg reduce/scale + t constraints ----------
// grid 2048 = 16 rg(16 rows) x 128 cb(128 cols): XCD-affine with pgemm's cb.
__global__ __launch_bounds__(256) void k_vscale(
    float* __restrict__ out_rw, const float* __restrict__ rowL,
    const u16* __restrict__ HgPart, const float* __restrict__ t0,
    float* __restrict__ tstep, const float* __restrict__ Wt_up,
    const float* __restrict__ bt_up, float* __restrict__ ts_out,
    u16* __restrict__ xn, float* __restrict__ Hgf, int r)
{
  const int b = blockIdx.x, tid = threadIdx.x;
  const int rg = b >> 7, cb = b & 127;
  const int row = rg * 16 + (tid >> 4);
  const int coff = (tid & 15) * 8;
  const float R = 1.0f / rowL[row];
  float* orow = out_rw + (size_t)row * RWN + (size_t)r * N + cb * 128 + coff;
  f32x4 x0 = *(const f32x4*)orow;
  f32x4 x1 = *(const f32x4*)(orow + 4);
  #pragma unroll
  for (int e = 0; e < 4; ++e) { x0[e] *= R; x1[e] *= R; }
  *(f32x4*)orow = x0;
  *(f32x4*)(orow + 4) = x1;

  if ((b & 15) == 8) {          // 128 blocks: Hg reduce over 128 chunks + scale + xn write
    const int idx = (b >> 4) * 256 + tid;
    float s0 = 0.f, s1 = 0.f, s2 = 0.f, s3 = 0.f;
    #pragma unroll 4
    for (int c = 0; c < 128; c += 4) {
      s0 += bf2f(HgPart[(size_t)(c + 0) * (B * HIN) + idx]);
      s1 += bf2f(HgPart[(size_t)(c + 1) * (B * HIN) + idx]);
      s2 += bf2f(HgPart[(size_t)(c + 2) * (B * HIN) + idx]);
      s3 += bf2f(HgPart[(size_t)(c + 3) * (B * HIN) + idx]);
    }
    float hg = ((s0 + s1) + (s2 + s3)) / rowL[idx >> 7];
    Hgf[idx] = hg;
    xn[(idx >> 7) * KC2 + (idx & 127)] = f2bf(hg);
  }

  if (b == 2047) {              // t constraints + Ht + ts/tstep
    __shared__ float red[256];
    float tv = t0[tid];
    red[tid] = tv; __syncthreads();
    for (int s = 128; s > 0; s >>= 1) {
      if (tid < s) red[tid] = fminf(red[tid], red[tid + s]);
      __syncthreads();
    }
    float mn = red[0]; __syncthreads();
    if (mn < 0.1f) tv -= mn;
    red[tid] = tv; __syncthreads();
    for (int s = 128; s > 0; s >>= 1) {
      if (tid < s) red[tid] = fmaxf(red[tid], red[tid + s]);
      __syncthreads();
    }
    float mx = red[0];
    if (mx > 1.0f) tv /= mx;
    tv = fminf(fmaxf(tv, tstep[r * B + tid]), 1.0f);
    tstep[(r + 1) * B + tid] = tv;
    ts_out[tid * RW + r] = tv;
    #pragma unroll 4
    for (int j = 0; j < HT; ++j)
      xn[tid * KC2 + HIN + j] = f2bf(tv * Wt_up[j] + bt_up[j]);
  }
}

__global__ __launch_bounds__(256) void k_prob(
    const float* __restrict__ Hgf, const float* __restrict__ tstep,
    const float* __restrict__ Wt_up, const float* __restrict__ bt_up,
    const float* __restrict__ wpc, float* __restrict__ outp)
{
  int b = threadIdx.x;
  float acc = 0.0f;
  for (int m = 0; m < HIN; ++m) acc += Hgf[b * HIN + m] * wpc[m];
  float tv = tstep[16 * B + b];
  for (int j = 0; j < HT; ++j) acc += (tv * Wt_up[j] + bt_up[j]) * wpc[HIN + j];
  outp[b] = acc;
}

// ---------- launch ----------
extern "C" void kernel_launch(void* const* d_in, const int* in_sizes, int n_in,
                              void* d_out, int out_size, void* d_ws, size_t ws_size,
                              hipStream_t stream) {
  (void)in_sizes; (void)n_in; (void)out_size; (void)ws_size;
  const float* latent  = (const float*)d_in[0];
  const float* inputs0 = (const float*)d_in[1];
  const float* Wc      = (const float*)d_in[2];
  const float* bc      = (const float*)d_in[3];
  const float* Ws      = (const float*)d_in[4];
  const float* bs      = (const float*)d_in[5];
  const float* Wh      = (const float*)d_in[6];
  const float* bh      = (const float*)d_in[7];
  const float* Wcc     = (const float*)d_in[8];
  const float* bcc     = (const float*)d_in[9];
  const float* W_ih    = (const float*)d_in[10];
  const float* b_ih    = (const float*)d_in[11];
  const float* W_hh    = (const float*)d_in[12];
  const float* b_hh    = (const float*)d_in[13];
  const float* W_up    = (const float*)d_in[14];
  const float* b_up    = (const float*)d_in[15];
  const float* W_down  = (const float*)d_in[16];
  const float* Wt_down = (const float*)d_in[17];
  const float* bt_down = (const float*)d_in[18];
  const float* Wt_pred = (const float*)d_in[19];
  const float* Wt_up   = (const float*)d_in[20];
  const float* bt_up   = (const float*)d_in[21];
  const float* W_vt    = (const float*)d_in[22];
  const float* W_prob  = (const float*)d_in[23];
  const float* gumbel  = (const float*)d_in[24];
  const float* drop_u  = (const float*)d_in[25];
  float* out = (float*)d_out;

  char* p = (char*)d_ws;
  auto alloc = [&](size_t bytes) { char* r = p; p += (bytes + 255) & ~(size_t)255; return r; };
  u16*   Wup_b  = (u16*)  alloc((size_t)N * H * 2);
  u16*   Wdn_b  = (u16*)  alloc((size_t)HIN * N * 2);
  u16*   Wfull_b= (u16*)  alloc((size_t)4 * H * KC2 * 2);
  u16*   Wtd_b  = (u16*)  alloc((size_t)HT * H * 2);
  u16*   Whc_b  = (u16*)  alloc((size_t)2 * H * H * 2);
  float* bcomb  = (float*)alloc(4 * H * 4);
  u16*   xcat0  = (u16*)  alloc((size_t)B * KC2 * 2);
  u16*   xcat1  = (u16*)  alloc((size_t)B * KC2 * 2);
  float* cbuf   = (float*)alloc((size_t)B * H * 4);
  u16*   sinit_b= (u16*)  alloc((size_t)B * H * 2);
  float* latbuf = (float*)alloc((size_t)B * HIN * 4);
  float* rowL   = (float*)alloc(B * 4);
  float* t0buf  = (float*)alloc(B * 4);
  float* tstep  = (float*)alloc((size_t)17 * B * 4);
  u16*   HgPart = (u16*)  alloc((size_t)128 * B * HIN * 2);
  float* Hgf    = (float*)alloc((size_t)B * HIN * 4);
  float* g0add  = (float*)alloc((size_t)B * 4 * H * 4);
  float* wpc    = (float*)alloc(160 * 4);

  k_prep<<<2048, 256, 0, stream>>>(W_up, W_down, W_hh, Wt_down, b_ih, b_hh, Wh, Wcc,
                                   Wup_b, Wdn_b, Wfull_b, Wtd_b, Whc_b, bcomb, xcat0, tstep);
  k_fold<<<3330, 256, 0, stream>>>(W_ih, W_vt, inputs0, W_prob, Wfull_b, g0add, wpc);
  k_lat  <<<128, 256, 0, stream>>>(latent, Wc, bc, latbuf);
  k_sinit<<<512, 256, 0, stream>>>(latbuf, Ws, bs, sinit_b);
  k_h0c0m<<<1024, 256, 0, stream>>>(sinit_b, Whc_b, bh, bcc, cbuf, xcat0);

  for (int r = 0; r < 16; ++r) {
    u16* xc = (r & 1) ? xcat1 : xcat0;
    u16* xn = (r & 1) ? xcat0 : xcat1;
    k_lstm <<<512, 256, 0, stream>>>(xc, Wfull_b, bcomb, cbuf, xn,
                                     r == 0 ? g0add : (const float*)nullptr, rowL);
    k_pgemm<<<1024, 256, 0, stream>>>(xn, Wup_b, b_up, gumbel + (size_t)r * B * N,
                                      out, rowL, HgPart, Wdn_b,
                                      Wtd_b, bt_down, Wt_pred, drop_u + (size_t)r * B * HT,
                                      t0buf, r);
    k_vscale<<<2048, 256, 0, stream>>>(out, rowL, HgPart, t0buf, tstep, Wt_up, bt_up,
                                       out + TS_OFF, xn, Hgf, r);
  }
  k_prob<<<1, 256, 0, stream>>>(Hgf, tstep, Wt_up, bt_up, wpc, out + PROB_OFF);
}